// Round 13
// baseline (380.704 us; speedup 1.0000x reference)
//
#include <hip/hip_runtime.h>
#include <hip/hip_bf16.h>
#include <stdint.h>

#define S_LEN 2048
#define NB 2
#define NH 16
#define HDIM 128
#define RDIM 64
#define DF 192          // HDIM + RDIM
#define MROWS 4096      // NB * S_LEN

typedef __bf16 bf16_t;
typedef __attribute__((ext_vector_type(8))) __bf16 bf16x8;
typedef __attribute__((ext_vector_type(4))) __bf16 bf16x4;
typedef __attribute__((ext_vector_type(4))) float f32x4;
typedef __attribute__((ext_vector_type(4))) float float4v;

__device__ __forceinline__ void gload_lds16(const bf16_t* g, bf16_t* l) {
  __builtin_amdgcn_global_load_lds(
      (const __attribute__((address_space(1))) void*)g,
      (__attribute__((address_space(3))) void*)l, 16, 0, 0);
}

// ---------------- convert f32 -> bf16 (contiguous) ----------------
__global__ __launch_bounds__(256) void convert_bf16(const float* __restrict__ in,
                                                    bf16_t* __restrict__ out, int n4) {
  int i = blockIdx.x * 256 + threadIdx.x;
  if (i >= n4) return;
  float4v v = *reinterpret_cast<const float4v*>(&in[(size_t)i * 4]);
  bf16x4 o;
  o[0] = (bf16_t)v[0]; o[1] = (bf16_t)v[1]; o[2] = (bf16_t)v[2]; o[3] = (bf16_t)v[3];
  *reinterpret_cast<bf16x4*>(&out[(size_t)i * 4]) = o;
}

// ---------------- fused transpose: all 8 weights in one launch ----------------
struct TrDesc { const float* src; bf16_t* dst; int K; int N; int nbx; int base; };
struct TrPack { TrDesc d[8]; };

__global__ __launch_bounds__(256) void transpose_all(TrPack p) {
  __shared__ float t[64][65];
  const int bid = blockIdx.x;
  int m = 0;
#pragma unroll
  for (int i = 1; i < 8; ++i) m += (bid >= p.d[i].base);
  const TrDesc td = p.d[m];
  const int local = bid - td.base;
  const int n0 = (local % td.nbx) * 64, k0 = (local / td.nbx) * 64;
  const int tx = threadIdx.x & 63, ty = threadIdx.x >> 6;
#pragma unroll
  for (int i = ty; i < 64; i += 4)
    t[i][tx] = td.src[(size_t)(k0 + i) * td.N + n0 + tx];
  __syncthreads();
#pragma unroll
  for (int i = ty; i < 64; i += 4)
    td.dst[(size_t)(n0 + i) * td.K + k0 + tx] = (bf16_t)t[tx][i];
}

// ---------------- GEMM: 256x256 tile, BK=64, 8 waves, 128x64 per wave ----------------
// Template geometry (m201): WARPS_M=2 x WARPS_N=4; per-wave acc[8][4] (128 VGPR).
// B-fragments (8 x bf16x8) loaded ONCE per K-tile (phase 0), reused in all 4
// phases -> 24 ds_read_b128 per 64 MFMA per wave (0.375/MFMA): LDS pipe no
// longer the cap. LDS 128 KB dbuf -> 1 block/CU (template regime).
// Per K-tile, 4 phases of 16 MFMA:
//   {ds_read frags | stage (4 issues at p0, 4 at p1) | [p3: vmcnt(0), loads
//    >=2.5 phases old] | barrier | lgkmcnt(0)+sched_barrier | setprio(1)
//    16 MFMA setprio(0) | barrier}
// A/B XOR-swizzle (chunk ^= row&7) verified 0-conflict (r9/r10).
struct EpiParams {
  bf16_t* o0;
  bf16_t* o1;
  bf16_t* o2;
  float* outf;
  const float* bias;
  const float* cosb;
  const float* sinb;
};

template <int MODE>
__device__ __forceinline__ void gemm_body(const bf16_t* __restrict__ A,
                                          const bf16_t* __restrict__ Bt,
                                          int N, int K, int m0, int n0,
                                          bf16_t (*Ab)[256 * 64],
                                          bf16_t (*Bb)[256 * 64], EpiParams ep) {
  const int tid = threadIdx.x;
  const int lane = tid & 63, w = tid >> 6;    // 8 waves: 2M x 4N
  const int l15 = lane & 15, lg = lane >> 4;
  const int mw = (w >> 2) * 128, nw = (w & 3) * 64;
  const int nt = K >> 6;

  auto stage = [&](int t, int buf, int j) {   // j = 0..3 A, 4..7 B
    const int s = (j & 3) * 512 + tid;
    const int row = s >> 3, c = s & 7;
    const int cs = c ^ (row & 7);
    if (j < 4)
      gload_lds16(A + (size_t)(m0 + row) * K + (t << 6) + cs * 8, &Ab[buf][s * 8]);
    else
      gload_lds16(Bt + (size_t)(n0 + row) * K + (t << 6) + cs * 8, &Bb[buf][s * 8]);
  };

  f32x4 acc[8][4] = {};
#pragma unroll
  for (int j = 0; j < 8; ++j) stage(0, 0, j);
  asm volatile("s_waitcnt vmcnt(0)" ::: "memory");
  __builtin_amdgcn_s_barrier();

  for (int t = 0; t < nt; ++t) {
    const int cur = t & 1;
    const bool pf = (t + 1 < nt);
    bf16x8 bfrag[4][2];                        // persists across phases
#pragma unroll
    for (int p = 0; p < 4; ++p) {
      // ---- ds_read fragments for this phase ----
      if (p == 0) {
#pragma unroll
        for (int j = 0; j < 4; ++j)
#pragma unroll
          for (int kk = 0; kk < 2; ++kk) {
            const int r = nw + j * 16 + l15;
            const int c = kk * 4 + lg;
            bfrag[j][kk] = *reinterpret_cast<const bf16x8*>(
                &Bb[cur][r * 64 + ((c ^ (r & 7)) << 3)]);
          }
      }
      bf16x8 afrag[2][2];
#pragma unroll
      for (int di = 0; di < 2; ++di)
#pragma unroll
        for (int kk = 0; kk < 2; ++kk) {
          const int r = mw + (p * 2 + di) * 16 + l15;
          const int c = kk * 4 + lg;
          afrag[di][kk] = *reinterpret_cast<const bf16x8*>(
              &Ab[cur][r * 64 + ((c ^ (r & 7)) << 3)]);
        }
      // ---- stage next tile: front-loaded (4 issues p0, 4 issues p1) ----
      if (pf) {
        if (p == 0) { stage(t + 1, cur ^ 1, 0); stage(t + 1, cur ^ 1, 1);
                      stage(t + 1, cur ^ 1, 2); stage(t + 1, cur ^ 1, 3); }
        if (p == 1) { stage(t + 1, cur ^ 1, 4); stage(t + 1, cur ^ 1, 5);
                      stage(t + 1, cur ^ 1, 6); stage(t + 1, cur ^ 1, 7); }
      }
      if (p == 3) asm volatile("s_waitcnt vmcnt(0)" ::: "memory");  // t+1 landed
      __builtin_amdgcn_s_barrier();
      asm volatile("s_waitcnt lgkmcnt(0)" ::: "memory");
      __builtin_amdgcn_sched_barrier(0);
      __builtin_amdgcn_s_setprio(1);
#pragma unroll
      for (int kk = 0; kk < 2; ++kk)
#pragma unroll
        for (int di = 0; di < 2; ++di)
#pragma unroll
          for (int j = 0; j < 4; ++j)
            acc[p * 2 + di][j] = __builtin_amdgcn_mfma_f32_16x16x32_bf16(
                afrag[di][kk], bfrag[j][kk], acc[p * 2 + di][j], 0, 0, 0);
      __builtin_amdgcn_s_setprio(0);
      __builtin_amdgcn_s_barrier();
    }
  }

#pragma unroll
  for (int i = 0; i < 8; ++i)
#pragma unroll
    for (int j = 0; j < 4; ++j) {
      const int col = n0 + nw + j * 16 + l15;
#pragma unroll
      for (int r = 0; r < 4; ++r) {
        const int row = m0 + mw + i * 16 + lg * 4 + r;
        float v = acc[i][j][r];
        const int b = row >> 11, s = row & 2047;
        if constexpr (MODE == 1) {
          ep.outf[(size_t)row * N + col] = v + ep.bias[col];
        } else if constexpr (MODE == 5) {
          if (col < 1536) {
            ep.o0[(size_t)row * 1536 + col] = (bf16_t)v;
          } else if (col < 2048) {
            ep.o1[(size_t)row * 512 + (col - 1536)] = (bf16_t)v;
          } else {
            const int c2 = col - 2048;
            float vb = v + ep.bias[c2];
            float other = __shfl_xor(vb, 1, 64);
            const int h = c2 >> 6, dr = c2 & 63;
            const int fi = dr >> 1;
            const float c = ep.cosb[s * 32 + fi];
            const float sn = ep.sinb[s * 32 + fi];
            const float o = (c2 & 1) ? (other * sn + vb * c) : (vb * c - other * sn);
            ep.o2[(((size_t)(b * NH + h)) * S_LEN + s) * DF + 128 + dr] = (bf16_t)o;
          }
        } else if constexpr (MODE == 6) {
          if (col < 2048) {
            const int h = col >> 7, d = col & 127;
            ep.o0[(((size_t)(b * NH + h)) * S_LEN + s) * DF + d] = (bf16_t)v;
          } else {
            const int c2 = col - 2048;
            float vb = v + ep.bias[c2];
            float other = __shfl_xor(vb, 1, 64);
            const int h = c2 >> 6, dr = c2 & 63;
            const int fi = dr >> 1;
            const float c = ep.cosb[s * 32 + fi];
            const float sn = ep.sinb[s * 32 + fi];
            const float o = (c2 & 1) ? (other * sn + vb * c) : (vb * c - other * sn);
            ep.o0[(((size_t)(b * NH + h)) * S_LEN + s) * DF + 128 + dr] = (bf16_t)o;
          }
        } else {  // MODE 7
          if (col < 2048) {
            const int h = col >> 7, d = col & 127;
            ep.o0[(((size_t)(b * NH + h)) * S_LEN + s) * DF + d] = (bf16_t)v;
          } else {
            const int c2 = col - 2048;
            const int h = c2 >> 7, d = c2 & 127;
            ep.o1[(((size_t)(b * NH + h)) * HDIM + d) * S_LEN + s] = (bf16_t)v;
          }
        }
      }
    }
}

template <int MODE>
__global__ __launch_bounds__(512, 2) void gemm_t8(const bf16_t* __restrict__ A,
                                                  const bf16_t* __restrict__ Bt,
                                                  int N, int K, EpiParams ep) {
  __shared__ alignas(16) bf16_t Ab[2][256 * 64];   // 64 KB
  __shared__ alignas(16) bf16_t Bb[2][256 * 64];   // 64 KB
  const int nwg = gridDim.x;
  int f = blockIdx.x;
  f = (f & 7) * (nwg >> 3) + (f >> 3);        // T1 XCD swizzle (nwg % 8 == 0)
  const int nbx = N >> 8;
  const int m0 = (f / nbx) * 256, n0 = (f % nbx) * 256;
  gemm_body<MODE>(A, Bt, N, K, m0, n0, Ab, Bb, ep);
}

// Fused: blocks [0,192) MODE 6 (N=3072,K=1536); [192,448) MODE 7 (N=4096,K=512).
__global__ __launch_bounds__(512, 2) void gemm_t867(const bf16_t* __restrict__ A6,
                                                    const bf16_t* __restrict__ Bt6,
                                                    const bf16_t* __restrict__ A7,
                                                    const bf16_t* __restrict__ Bt7,
                                                    EpiParams ep6, EpiParams ep7) {
  __shared__ alignas(16) bf16_t Ab[2][256 * 64];
  __shared__ alignas(16) bf16_t Bb[2][256 * 64];
  const int bid = blockIdx.x;
  if (bid < 192) {
    int f = (bid & 7) * 24 + (bid >> 3);      // T1 within 192
    const int m0 = (f / 12) * 256, n0 = (f % 12) * 256;
    gemm_body<6>(A6, Bt6, 3072, 1536, m0, n0, Ab, Bb, ep6);
  } else {
    int b2 = bid - 192;
    int f = (b2 & 7) * 32 + (b2 >> 3);        // T1 within 256
    const int m0 = (f / 16) * 256, n0 = (f % 16) * 256;
    gemm_body<7>(A7, Bt7, 4096, 512, m0, n0, Ab, Bb, ep7);
  }
}

// ---------------- flash attention (causal), swapped softmax, 32q/wave ----------------
// (unchanged from r8: 4 waves x 32 q-rows, swapped QK^T, defer-max, 56 KB LDS)
__global__ __launch_bounds__(256, 2) void attn_fwd(const bf16_t* __restrict__ qf,
                                                   const bf16_t* __restrict__ kf,
                                                   const bf16_t* __restrict__ vT,
                                                   bf16_t* __restrict__ att) {
  const int tid = threadIdx.x;
  const int lane = tid & 63, w = tid >> 6;   // w: 0..3
  const int l15 = lane & 15, lg = lane >> 4;
  const int l = blockIdx.x;                  // 0..511
  const int bh = (l & 7) * 4 + ((l >> 3) & 3);
  const int qchunk = l >> 5;                 // 0..15
  const int qb0 = (15 - qchunk) * 128;
  const int q0 = qb0 + w * 32;
  const float scale = 0.07216878364870322f;  // 1/sqrt(192)

  __shared__ alignas(16) bf16_t Ks[64 * 192];
  __shared__ alignas(16) bf16_t Vs[128 * 64];
  __shared__ alignas(16) bf16_t Ps[4 * 2048];

  bf16x8 qfr[2][6];
#pragma unroll
  for (int mf = 0; mf < 2; ++mf) {
    const bf16_t* qptr = qf + ((size_t)bh * S_LEN + q0 + mf * 16 + l15) * DF + lg * 8;
#pragma unroll
    for (int d = 0; d < 6; ++d)
      qfr[mf][d] = *reinterpret_cast<const bf16x8*>(qptr + d * 32);
  }

  f32x4 o[2][8] = {};
  float mrun[2] = {-1e30f, -1e30f}, lsum[2] = {0.0f, 0.0f};

  const bf16_t* kb0 = kf + (size_t)bh * S_LEN * DF;
  const bf16_t* vb0 = vT + (size_t)bh * HDIM * S_LEN;
  const int njt = qb0 / 64 + 2;
  const int wslot = tid & ~63;

  for (int jt = 0; jt < njt; ++jt) {
    const int j0 = jt * 64;
    __syncthreads();
    const bf16_t* kTile = kb0 + (size_t)j0 * DF;
#pragma unroll
    for (int i = 0; i < 6; ++i) {
      const int s = i * 256 + tid;
      const int row = s / 24;
      const int c = s - row * 24;
      const int cs = c ^ (row & 7);
      gload_lds16(kTile + (size_t)row * DF + cs * 8,
                  Ks + (size_t)(i * 256 + wslot) * 8);
    }
    const bf16_t* vTile = vb0 + j0;
#pragma unroll
    for (int i = 0; i < 4; ++i) {
      const int s = i * 256 + tid;
      const int row = s >> 3;
      const int c = s & 7;
      const int cs = c ^ (row & 7);
      gload_lds16(vTile + (size_t)row * S_LEN + cs * 8,
                  Vs + (size_t)(i * 256 + wslot) * 8);
    }
    __syncthreads();

    if (j0 > q0 + 31) continue;

    f32x4 sa[2][4] = {};
    __builtin_amdgcn_s_setprio(1);
#pragma unroll
    for (int jf = 0; jf < 4; ++jf) {
      const int krow = jf * 16 + l15;
      const int ksw = krow & 7;
#pragma unroll
      for (int d = 0; d < 6; ++d) {
        const int kc = (4 * d + lg) ^ ksw;
        bf16x8 kfr = *reinterpret_cast<const bf16x8*>(&Ks[krow * 192 + kc * 8]);
#pragma unroll
        for (int mf = 0; mf < 2; ++mf)
          sa[mf][jf] =
              __builtin_amdgcn_mfma_f32_16x16x32_bf16(kfr, qfr[mf][d], sa[mf][jf], 0, 0, 0);
      }
    }
    __builtin_amdgcn_s_setprio(0);

#pragma unroll
    for (int mf = 0; mf < 2; ++mf) {
      const int qi = q0 + mf * 16 + l15;
      const bool full = (j0 + 63 <= q0 + mf * 16);
      float sv[16];
#pragma unroll
      for (int jf = 0; jf < 4; ++jf)
#pragma unroll
        for (int r = 0; r < 4; ++r) {
          float x = sa[mf][jf][r] * scale;
          if (!full) {
            const int j = j0 + jf * 16 + lg * 4 + r;
            if (j > qi) x = -1e30f;
          }
          sv[jf * 4 + r] = x;
        }

      float a8[8];
#pragma unroll
      for (int i = 0; i < 8; ++i) a8[i] = fmaxf(sv[i], sv[i + 8]);
#pragma unroll
      for (int i = 0; i < 4; ++i) a8[i] = fmaxf(a8[i], a8[i + 4]);
      float mx = fmaxf(fmaxf(a8[0], a8[1]), fmaxf(a8[2], a8[3]));
      mx = fmaxf(mx, __shfl_xor(mx, 16, 64));
      mx = fmaxf(mx, __shfl_xor(mx, 32, 64));

      if (__any(mx > mrun[mf] + 8.0f)) {
        const float mn = fmaxf(mrun[mf], mx);
        const float alpha = __expf(mrun[mf] - mn);
        mrun[mf] = mn;
        lsum[mf] *= alpha;
        float af[4];
#pragma unroll
        for (int r = 0; r < 4; ++r) af[r] = __shfl(alpha, lg * 4 + r, 16);
#pragma unroll
        for (int dt = 0; dt < 8; ++dt)
#pragma unroll
          for (int r = 0; r < 4; ++r) o[mf][dt][r] *= af[r];
      }

#pragma unroll
      for (int i = 0; i < 16; ++i) sv[i] = __expf(sv[i] - mrun[mf]);
      float s8[8];
#pragma unroll
      for (int i = 0; i < 8; ++i) s8[i] = sv[i] + sv[i + 8];
#pragma unroll
      for (int i = 0; i < 4; ++i) s8[i] = s8[i] + s8[i + 4];
      float sm = (s8[0] + s8[1]) + (s8[2] + s8[3]);
      sm += __shfl_xor(sm, 16, 64);
      sm += __shfl_xor(sm, 32, 64);
      lsum[mf] += sm;

#pragma unroll
      for (int jf = 0; jf < 4; ++jf) {
        bf16x4 pk;
#pragma unroll
        for (int r = 0; r < 4; ++r) pk[r] = (bf16_t)sv[jf * 4 + r];
        const int key = jf * 16 + lg * 4;
        *reinterpret_cast<bf16x4*>(
            &Ps[w * 2048 + mf * 1024 + l15 * 64 + (key ^ ((l15 & 7) << 3))]) = pk;
      }
    }
    asm volatile("s_waitcnt lgkmcnt(0)" ::: "memory");
    __builtin_amdgcn_sched_barrier(0);
    bf16x8 pfr[2][2];
#pragma unroll
    for (int mf = 0; mf < 2; ++mf)
#pragma unroll
      for (int jk = 0; jk < 2; ++jk)
        pfr[mf][jk] = *reinterpret_cast<const bf16x8*>(
            &Ps[w * 2048 + mf * 1024 + l15 * 64 + (((jk * 4 + lg) ^ (l15 & 7)) << 3)]);

    __builtin_amdgcn_s_setprio(1);
#pragma unroll
    for (int dt = 0; dt < 8; ++dt) {
      const int vrow = dt * 16 + l15;
      const int vsw = vrow & 7;
#pragma unroll
      for (int jk = 0; jk < 2; ++jk) {
        const int vc = (jk * 4 + lg) ^ vsw;
        bf16x8 vfr = *reinterpret_cast<const bf16x8*>(&Vs[vrow * 64 + vc * 8]);
#pragma unroll
        for (int mf = 0; mf < 2; ++mf)
          o[mf][dt] =
              __builtin_amdgcn_mfma_f32_16x16x32_bf16(pfr[mf][jk], vfr, o[mf][dt], 0, 0, 0);
      }
    }
    __builtin_amdgcn_s_setprio(0);
  }

  const int b = bh >> 4, h = bh & 15;
#pragma unroll
  for (int mf = 0; mf < 2; ++mf) {
    const float inv = 1.0f / lsum[mf];
    float iv[4];
#pragma unroll
    for (int r = 0; r < 4; ++r) iv[r] = __shfl(inv, lg * 4 + r, 16);
#pragma unroll
    for (int dt = 0; dt < 8; ++dt)
#pragma unroll
      for (int r = 0; r < 4; ++r) {
        const int s = q0 + mf * 16 + lg * 4 + r;
        att[((size_t)b * S_LEN + s) * 2048 + h * 128 + dt * 16 + l15] =
            (bf16_t)(o[mf][dt][r] * iv[r]);
      }
  }
}

// ---------------- host launch ----------------
extern "C" void kernel_launch(void* const* d_in, const int* in_sizes, int n_in,
                              void* d_out, int out_size, void* d_ws, size_t ws_size,
                              hipStream_t stream) {
  const float* x    = (const float*)d_in[0];
  const float* fcos = (const float*)d_in[1];
  const float* fsin = (const float*)d_in[2];
  const float* Wkv  = (const float*)d_in[3];
  const float* Wlq  = (const float*)d_in[4];
  const float* Wq   = (const float*)d_in[5];
  const float* Wk   = (const float*)d_in[6];
  const float* Wv   = (const float*)d_in[7];
  const float* Wqr  = (const float*)d_in[8];
  const float* bqr  = (const float*)d_in[9];
  const float* Wkr  = (const float*)d_in[10];
  const float* bkr  = (const float*)d_in[11];
  const float* Wo   = (const float*)d_in[12];
  const float* bo   = (const float*)d_in[13];
  float* out = (float*)d_out;

  char* ws = (char*)d_ws;
  size_t off = 0;
  auto alloc = [&](size_t bytes) {
    void* p = ws + off;
    off += (bytes + 255) & ~(size_t)255;
    return p;
  };
  bf16_t* xb    = (bf16_t*)alloc((size_t)MROWS * 2048 * 2);
  bf16_t* WcatA = (bf16_t*)alloc((size_t)3072 * 2048 * 2);  // [Wlq|Wkv|Wkr]^T, K=2048
  bf16_t* WcatB = (bf16_t*)alloc((size_t)3072 * 1536 * 2);  // [Wq|Wqr]^T,     K=1536
  bf16_t* WcatC = (bf16_t*)alloc((size_t)4096 * 512 * 2);   // [Wk|Wv]^T,      K=512
  bf16_t* WoT   = (bf16_t*)alloc((size_t)2048 * 2048 * 2);
  bf16_t* cq    = (bf16_t*)alloc((size_t)MROWS * 1536 * 2);
  bf16_t* ckv   = (bf16_t*)alloc((size_t)MROWS * 512 * 2);
  bf16_t* qfb   = (bf16_t*)alloc((size_t)NB * NH * S_LEN * DF * 2);
  bf16_t* kfb   = (bf16_t*)alloc((size_t)NB * NH * S_LEN * DF * 2);
  bf16_t* vTb   = (bf16_t*)alloc((size_t)NB * NH * HDIM * S_LEN * 2);
  bf16_t* attb  = (bf16_t*)alloc((size_t)MROWS * 2048 * 2);

  // 1. convert x
  {
    int n4 = (MROWS * 2048) / 4;
    convert_bf16<<<dim3((n4 + 255) / 256), dim3(256), 0, stream>>>(x, xb, n4);
  }
  // 2. all 8 transposes in one launch
  {
    TrPack p;
    int base = 0;
    auto set = [&](int i, const float* s, bf16_t* d, int K, int N) {
      p.d[i] = {s, d, K, N, N / 64, base};
      base += (N / 64) * (K / 64);
    };
    set(0, Wlq, WcatA, 2048, 1536);
    set(1, Wkv, WcatA + (size_t)1536 * 2048, 2048, 512);
    set(2, Wkr, WcatA + (size_t)2048 * 2048, 2048, 1024);
    set(3, Wq,  WcatB, 1536, 2048);
    set(4, Wqr, WcatB + (size_t)2048 * 1536, 1536, 1024);
    set(5, Wk,  WcatC, 512, 2048);
    set(6, Wv,  WcatC + (size_t)2048 * 512, 512, 2048);
    set(7, Wo,  WoT, 2048, 2048);
    transpose_all<<<dim3(base), dim3(256), 0, stream>>>(p);
  }

  EpiParams ep{}, ep2{};

  // 3. fused: [cq | ckv | kr-rope->kf] = xb @ WcatA^T   (N=3072, K=2048), 192 blocks
  ep = {cq, ckv, kfb, nullptr, bkr, fcos, fsin};
  gemm_t8<5><<<dim3(192), dim3(512), 0, stream>>>(xb, WcatA, 3072, 2048, ep);
  // 4+5. fused single launch: {q,qr->qf} and {k->kf, v->vT}, 192+256 blocks
  ep  = {qfb, nullptr, nullptr, nullptr, bqr, fcos, fsin};
  ep2 = {kfb, vTb, nullptr, nullptr, nullptr, nullptr, nullptr};
  gemm_t867<<<dim3(448), dim3(512), 0, stream>>>(cq, WcatB, ckv, WcatC, ep, ep2);
  // 6. attention
  attn_fwd<<<dim3(512), dim3(256), 0, stream>>>(qfb, kfb, vTb, attb);
  // 7. out = att @ Wo + bo  (f32), 128 blocks
  ep = {nullptr, nullptr, nullptr, out, bo, nullptr, nullptr};
  gemm_t8<1><<<dim3(128), dim3(512), 0, stream>>>(attb, WoT, 2048, 2048, ep);
}

// Round 14
// 376.097 us; speedup vs baseline: 1.0122x; 1.0122x over previous
//
#include <hip/hip_runtime.h>
#include <hip/hip_bf16.h>
#include <stdint.h>

#define S_LEN 2048
#define NB 2
#define NH 16
#define HDIM 128
#define RDIM 64
#define DF 192          // HDIM + RDIM
#define MROWS 4096      // NB * S_LEN

typedef __bf16 bf16_t;
typedef __attribute__((ext_vector_type(8))) __bf16 bf16x8;
typedef __attribute__((ext_vector_type(4))) __bf16 bf16x4;
typedef __attribute__((ext_vector_type(4))) float f32x4;
typedef __attribute__((ext_vector_type(4))) float float4v;

__device__ __forceinline__ void gload_lds16(const bf16_t* g, bf16_t* l) {
  __builtin_amdgcn_global_load_lds(
      (const __attribute__((address_space(1))) void*)g,
      (__attribute__((address_space(3))) void*)l, 16, 0, 0);
}

// ---------------- convert f32 -> bf16 (contiguous) ----------------
__global__ __launch_bounds__(256) void convert_bf16(const float* __restrict__ in,
                                                    bf16_t* __restrict__ out, int n4) {
  int i = blockIdx.x * 256 + threadIdx.x;
  if (i >= n4) return;
  float4v v = *reinterpret_cast<const float4v*>(&in[(size_t)i * 4]);
  bf16x4 o;
  o[0] = (bf16_t)v[0]; o[1] = (bf16_t)v[1]; o[2] = (bf16_t)v[2]; o[3] = (bf16_t)v[3];
  *reinterpret_cast<bf16x4*>(&out[(size_t)i * 4]) = o;
}

// ---------------- fused transpose: all 8 weights in one launch ----------------
struct TrDesc { const float* src; bf16_t* dst; int K; int N; int nbx; int base; };
struct TrPack { TrDesc d[8]; };

__global__ __launch_bounds__(256) void transpose_all(TrPack p) {
  __shared__ float t[64][65];
  const int bid = blockIdx.x;
  int m = 0;
#pragma unroll
  for (int i = 1; i < 8; ++i) m += (bid >= p.d[i].base);
  const TrDesc td = p.d[m];
  const int local = bid - td.base;
  const int n0 = (local % td.nbx) * 64, k0 = (local / td.nbx) * 64;
  const int tx = threadIdx.x & 63, ty = threadIdx.x >> 6;
#pragma unroll
  for (int i = ty; i < 64; i += 4)
    t[i][tx] = td.src[(size_t)(k0 + i) * td.N + n0 + tx];
  __syncthreads();
#pragma unroll
  for (int i = ty; i < 64; i += 4)
    td.dst[(size_t)(n0 + i) * td.K + k0 + tx] = (bf16_t)t[tx][i];
}

// ---------------- GEMM: 256x256, BK=64, 8-phase/2-K-tile template ----------------
// 8 waves (2M x 4N), per-wave C 128x64 (acc[8][4]). LDS 128 KB as
// [dbuf][half] 16 KB half-tiles of A and B; even K-tiles -> dbuf0, odd -> dbuf1.
// Per K-tile 4 phases, quadrant order (msub,nh)=(0,0),(0,1),(1,1),(1,0):
// ds_reads 12/4/8/0 (B-half frags kept live). Stage 1 half-tile (2 gload_lds)
// per phase: ph1:A1(2t+1) ph2:B0(2t+2) ph3:B1 ph4:A0 ph5:A1 ph6:B0(2t+3)
// ph7:B1 ph8:A0; vmcnt(6) ONLY at ph4/ph8 (3 half-tiles stay in flight ->
// every load gets >=4 phases before its wait). Stage-after-last-read checked
// per half-tile; phase barriers separate each. Swizzle chunk^=row&7 (verified).
struct EpiParams {
  bf16_t* o0;
  bf16_t* o1;
  bf16_t* o2;
  float* outf;
  const float* bias;
  const float* cosb;
  const float* sinb;
};

#define GEMM_MFMA(af, bf, I0, J0)                                              \
  __builtin_amdgcn_s_barrier();                                                \
  asm volatile("s_waitcnt lgkmcnt(0)" ::: "memory");                           \
  __builtin_amdgcn_sched_barrier(0);                                           \
  __builtin_amdgcn_s_setprio(1);                                               \
  _Pragma("unroll") for (int kk = 0; kk < 2; ++kk)                             \
  _Pragma("unroll") for (int i = 0; i < 4; ++i)                                \
  _Pragma("unroll") for (int j = 0; j < 2; ++j)                                \
      acc[(I0) + i][(J0) + j] = __builtin_amdgcn_mfma_f32_16x16x32_bf16(       \
          af[i][kk], bf[j][kk], acc[(I0) + i][(J0) + j], 0, 0, 0);             \
  __builtin_amdgcn_s_setprio(0);                                               \
  __builtin_amdgcn_s_barrier();

template <int MODE>
__device__ __forceinline__ void gemm8_body(const bf16_t* __restrict__ A,
                                           const bf16_t* __restrict__ Bt,
                                           int N, int K, int m0, int n0,
                                           bf16_t* __restrict__ Ah,  // [2][2][8192]
                                           bf16_t* __restrict__ Bh,
                                           EpiParams ep) {
  const int tid = threadIdx.x;
  const int lane = tid & 63, w = tid >> 6;    // 8 waves: 2M x 4N
  const int l15 = lane & 15, lg = lane >> 4;
  const int mg = w >> 2, ng = w & 3;
  const int mw = mg * 128, nw = ng * 64;
  const int bbase = (ng & 1) * 64;
  const int niter = K >> 7;                   // 2 K-tiles per iter

  auto stageHalf = [&](int kt, int u) {       // u: 0=A0 1=A1 2=B0 3=B1
    const int db = kt & 1;
    const int kof = kt << 6;
#pragma unroll
    for (int i = 0; i < 2; ++i) {
      const int s = i * 512 + tid;
      const int row = s >> 3, c = s & 7;
      const int cs = c ^ (row & 7);
      if (u == 0)
        gload_lds16(A + (size_t)(m0 + row) * K + kof + cs * 8,
                    Ah + (size_t)(db * 2 + 0) * 8192 + s * 8);
      else if (u == 1)
        gload_lds16(A + (size_t)(m0 + 128 + row) * K + kof + cs * 8,
                    Ah + (size_t)(db * 2 + 1) * 8192 + s * 8);
      else if (u == 2)
        gload_lds16(Bt + (size_t)(n0 + row) * K + kof + cs * 8,
                    Bh + (size_t)(db * 2 + 0) * 8192 + s * 8);
      else
        gload_lds16(Bt + (size_t)(n0 + 128 + row) * K + kof + cs * 8,
                    Bh + (size_t)(db * 2 + 1) * 8192 + s * 8);
    }
  };
  auto readA = [&](int db, int msub, bf16x8 a[4][2]) {
    const bf16_t* base = Ah + (size_t)(db * 2 + mg) * 8192;
#pragma unroll
    for (int i = 0; i < 4; ++i) {
      const int lrow = msub * 64 + i * 16 + l15;
#pragma unroll
      for (int kk = 0; kk < 2; ++kk) {
        const int c = kk * 4 + lg;
        a[i][kk] = *reinterpret_cast<const bf16x8*>(
            base + lrow * 64 + ((c ^ (lrow & 7)) << 3));
      }
    }
  };
  auto readB = [&](int db, int nh, bf16x8 b[2][2]) {
    const bf16_t* base = Bh + (size_t)(db * 2 + (ng >> 1)) * 8192;
#pragma unroll
    for (int j = 0; j < 2; ++j) {
      const int lrow = bbase + (nh * 2 + j) * 16 + l15;
#pragma unroll
      for (int kk = 0; kk < 2; ++kk) {
        const int c = kk * 4 + lg;
        b[j][kk] = *reinterpret_cast<const bf16x8*>(
            base + lrow * 64 + ((c ^ (lrow & 7)) << 3));
      }
    }
  };

  f32x4 acc[8][4] = {};
  // prologue: k0 fully + k1 {B0,B1,A0}; A1(k1) staged at iter0-ph1
  stageHalf(0, 0); stageHalf(0, 1); stageHalf(0, 2); stageHalf(0, 3);
  stageHalf(1, 2); stageHalf(1, 3); stageHalf(1, 0);
  asm volatile("s_waitcnt vmcnt(6)" ::: "memory");   // k0 landed
  __builtin_amdgcn_s_barrier();

  for (int t = 0; t < niter; ++t) {
    const bool pf = (t + 1 < niter);
    const int ke = 2 * t + 2, ko = 2 * t + 3;

#pragma unroll
    for (int half = 0; half < 2; ++half) {   // half 0: tile 2t (dbuf0); 1: 2t+1 (dbuf1)
      const int db = half;
      const int nx = (half == 0) ? ke : ko;  // tile staged during this half
      bf16x8 a0[4][2], a1[4][2], b0[2][2], b1[2][2];

      // ---- P0: A-sub0 + B-nh0 reads; stage A1 ----
      readA(db, 0, a0);
      readB(db, 0, b0);
      if (half == 0) stageHalf(2 * t + 1, 1);          // A1 of odd tile (always)
      else if (pf) stageHalf(ke, 1);                   // A1 of next even tile
      GEMM_MFMA(a0, b0, 0, 0)

      // ---- P1: B-nh1 reads; stage B0(nx) ----
      readB(db, 1, b1);
      if (pf) stageHalf(nx, 2);
      GEMM_MFMA(a0, b1, 0, 2)

      // ---- P2: A-sub1 reads; stage B1(nx) ----
      readA(db, 1, a1);
      if (pf) stageHalf(nx, 3);
      GEMM_MFMA(a1, b1, 4, 2)

      // ---- P3: no reads (b0 kept); stage A0(nx); counted vmcnt ----
      if (pf) {
        stageHalf(nx, 0);
        asm volatile("s_waitcnt vmcnt(6)" ::: "memory");  // 3 half-tiles in flight
      } else {
        asm volatile("s_waitcnt vmcnt(0)" ::: "memory");
      }
      GEMM_MFMA(a1, b0, 4, 0)
    }
  }

#pragma unroll
  for (int i = 0; i < 8; ++i)
#pragma unroll
    for (int j = 0; j < 4; ++j) {
      const int col = n0 + nw + j * 16 + l15;
#pragma unroll
      for (int r = 0; r < 4; ++r) {
        const int row = m0 + mw + i * 16 + lg * 4 + r;
        float v = acc[i][j][r];
        const int b = row >> 11, s = row & 2047;
        if constexpr (MODE == 1) {
          ep.outf[(size_t)row * N + col] = v + ep.bias[col];
        } else if constexpr (MODE == 5) {
          if (col < 1536) {
            ep.o0[(size_t)row * 1536 + col] = (bf16_t)v;
          } else if (col < 2048) {
            ep.o1[(size_t)row * 512 + (col - 1536)] = (bf16_t)v;
          } else {
            const int c2 = col - 2048;
            float vb = v + ep.bias[c2];
            float other = __shfl_xor(vb, 1, 64);
            const int h = c2 >> 6, dr = c2 & 63;
            const int fi = dr >> 1;
            const float c = ep.cosb[s * 32 + fi];
            const float sn = ep.sinb[s * 32 + fi];
            const float o = (c2 & 1) ? (other * sn + vb * c) : (vb * c - other * sn);
            ep.o2[(((size_t)(b * NH + h)) * S_LEN + s) * DF + 128 + dr] = (bf16_t)o;
          }
        } else if constexpr (MODE == 6) {
          if (col < 2048) {
            const int h = col >> 7, d = col & 127;
            ep.o0[(((size_t)(b * NH + h)) * S_LEN + s) * DF + d] = (bf16_t)v;
          } else {
            const int c2 = col - 2048;
            float vb = v + ep.bias[c2];
            float other = __shfl_xor(vb, 1, 64);
            const int h = c2 >> 6, dr = c2 & 63;
            const int fi = dr >> 1;
            const float c = ep.cosb[s * 32 + fi];
            const float sn = ep.sinb[s * 32 + fi];
            const float o = (c2 & 1) ? (other * sn + vb * c) : (vb * c - other * sn);
            ep.o0[(((size_t)(b * NH + h)) * S_LEN + s) * DF + 128 + dr] = (bf16_t)o;
          }
        } else {  // MODE 7
          if (col < 2048) {
            const int h = col >> 7, d = col & 127;
            ep.o0[(((size_t)(b * NH + h)) * S_LEN + s) * DF + d] = (bf16_t)v;
          } else {
            const int c2 = col - 2048;
            const int h = c2 >> 7, d = c2 & 127;
            ep.o1[(((size_t)(b * NH + h)) * HDIM + d) * S_LEN + s] = (bf16_t)v;
          }
        }
      }
    }
}

template <int MODE>
__global__ __launch_bounds__(512, 2) void gemm_8ph(const bf16_t* __restrict__ A,
                                                   const bf16_t* __restrict__ Bt,
                                                   int N, int K, EpiParams ep) {
  __shared__ alignas(16) bf16_t Ah[2 * 2 * 8192];   // 64 KB
  __shared__ alignas(16) bf16_t Bh[2 * 2 * 8192];   // 64 KB
  const int nwg = gridDim.x;
  int f = blockIdx.x;
  f = (f & 7) * (nwg >> 3) + (f >> 3);        // T1 XCD swizzle (nwg % 8 == 0)
  const int nbx = N >> 8;
  const int m0 = (f / nbx) * 256, n0 = (f % nbx) * 256;
  gemm8_body<MODE>(A, Bt, N, K, m0, n0, Ah, Bh, ep);
}

// Fused: blocks [0,192) MODE 6 (N=3072,K=1536); [192,448) MODE 7 (N=4096,K=512).
__global__ __launch_bounds__(512, 2) void gemm_8ph67(const bf16_t* __restrict__ A6,
                                                     const bf16_t* __restrict__ Bt6,
                                                     const bf16_t* __restrict__ A7,
                                                     const bf16_t* __restrict__ Bt7,
                                                     EpiParams ep6, EpiParams ep7) {
  __shared__ alignas(16) bf16_t Ah[2 * 2 * 8192];
  __shared__ alignas(16) bf16_t Bh[2 * 2 * 8192];
  const int bid = blockIdx.x;
  if (bid < 192) {
    int f = (bid & 7) * 24 + (bid >> 3);      // T1 within 192
    const int m0 = (f / 12) * 256, n0 = (f % 12) * 256;
    gemm8_body<6>(A6, Bt6, 3072, 1536, m0, n0, Ah, Bh, ep6);
  } else {
    int b2 = bid - 192;
    int f = (b2 & 7) * 32 + (b2 >> 3);        // T1 within 256
    const int m0 = (f / 16) * 256, n0 = (f % 16) * 256;
    gemm8_body<7>(A7, Bt7, 4096, 512, m0, n0, Ah, Bh, ep7);
  }
}

// ---------------- flash attention (causal), swapped softmax, 32q/wave ----------------
// (unchanged from r8: 4 waves x 32 q-rows, swapped QK^T, defer-max, 56 KB LDS)
__global__ __launch_bounds__(256, 2) void attn_fwd(const bf16_t* __restrict__ qf,
                                                   const bf16_t* __restrict__ kf,
                                                   const bf16_t* __restrict__ vT,
                                                   bf16_t* __restrict__ att) {
  const int tid = threadIdx.x;
  const int lane = tid & 63, w = tid >> 6;   // w: 0..3
  const int l15 = lane & 15, lg = lane >> 4;
  const int l = blockIdx.x;                  // 0..511
  const int bh = (l & 7) * 4 + ((l >> 3) & 3);
  const int qchunk = l >> 5;                 // 0..15
  const int qb0 = (15 - qchunk) * 128;
  const int q0 = qb0 + w * 32;
  const float scale = 0.07216878364870322f;  // 1/sqrt(192)

  __shared__ alignas(16) bf16_t Ks[64 * 192];
  __shared__ alignas(16) bf16_t Vs[128 * 64];
  __shared__ alignas(16) bf16_t Ps[4 * 2048];

  bf16x8 qfr[2][6];
#pragma unroll
  for (int mf = 0; mf < 2; ++mf) {
    const bf16_t* qptr = qf + ((size_t)bh * S_LEN + q0 + mf * 16 + l15) * DF + lg * 8;
#pragma unroll
    for (int d = 0; d < 6; ++d)
      qfr[mf][d] = *reinterpret_cast<const bf16x8*>(qptr + d * 32);
  }

  f32x4 o[2][8] = {};
  float mrun[2] = {-1e30f, -1e30f}, lsum[2] = {0.0f, 0.0f};

  const bf16_t* kb0 = kf + (size_t)bh * S_LEN * DF;
  const bf16_t* vb0 = vT + (size_t)bh * HDIM * S_LEN;
  const int njt = qb0 / 64 + 2;
  const int wslot = tid & ~63;

  for (int jt = 0; jt < njt; ++jt) {
    const int j0 = jt * 64;
    __syncthreads();
    const bf16_t* kTile = kb0 + (size_t)j0 * DF;
#pragma unroll
    for (int i = 0; i < 6; ++i) {
      const int s = i * 256 + tid;
      const int row = s / 24;
      const int c = s - row * 24;
      const int cs = c ^ (row & 7);
      gload_lds16(kTile + (size_t)row * DF + cs * 8,
                  Ks + (size_t)(i * 256 + wslot) * 8);
    }
    const bf16_t* vTile = vb0 + j0;
#pragma unroll
    for (int i = 0; i < 4; ++i) {
      const int s = i * 256 + tid;
      const int row = s >> 3;
      const int c = s & 7;
      const int cs = c ^ (row & 7);
      gload_lds16(vTile + (size_t)row * S_LEN + cs * 8,
                  Vs + (size_t)(i * 256 + wslot) * 8);
    }
    __syncthreads();

    if (j0 > q0 + 31) continue;

    f32x4 sa[2][4] = {};
    __builtin_amdgcn_s_setprio(1);
#pragma unroll
    for (int jf = 0; jf < 4; ++jf) {
      const int krow = jf * 16 + l15;
      const int ksw = krow & 7;
#pragma unroll
      for (int d = 0; d < 6; ++d) {
        const int kc = (4 * d + lg) ^ ksw;
        bf16x8 kfr = *reinterpret_cast<const bf16x8*>(&Ks[krow * 192 + kc * 8]);
#pragma unroll
        for (int mf = 0; mf < 2; ++mf)
          sa[mf][jf] =
              __builtin_amdgcn_mfma_f32_16x16x32_bf16(kfr, qfr[mf][d], sa[mf][jf], 0, 0, 0);
      }
    }
    __builtin_amdgcn_s_setprio(0);

#pragma unroll
    for (int mf = 0; mf < 2; ++mf) {
      const int qi = q0 + mf * 16 + l15;
      const bool full = (j0 + 63 <= q0 + mf * 16);
      float sv[16];
#pragma unroll
      for (int jf = 0; jf < 4; ++jf)
#pragma unroll
        for (int r = 0; r < 4; ++r) {
          float x = sa[mf][jf][r] * scale;
          if (!full) {
            const int j = j0 + jf * 16 + lg * 4 + r;
            if (j > qi) x = -1e30f;
          }
          sv[jf * 4 + r] = x;
        }

      float a8[8];
#pragma unroll
      for (int i = 0; i < 8; ++i) a8[i] = fmaxf(sv[i], sv[i + 8]);
#pragma unroll
      for (int i = 0; i < 4; ++i) a8[i] = fmaxf(a8[i], a8[i + 4]);
      float mx = fmaxf(fmaxf(a8[0], a8[1]), fmaxf(a8[2], a8[3]));
      mx = fmaxf(mx, __shfl_xor(mx, 16, 64));
      mx = fmaxf(mx, __shfl_xor(mx, 32, 64));

      if (__any(mx > mrun[mf] + 8.0f)) {
        const float mn = fmaxf(mrun[mf], mx);
        const float alpha = __expf(mrun[mf] - mn);
        mrun[mf] = mn;
        lsum[mf] *= alpha;
        float af[4];
#pragma unroll
        for (int r = 0; r < 4; ++r) af[r] = __shfl(alpha, lg * 4 + r, 16);
#pragma unroll
        for (int dt = 0; dt < 8; ++dt)
#pragma unroll
          for (int r = 0; r < 4; ++r) o[mf][dt][r] *= af[r];
      }

#pragma unroll
      for (int i = 0; i < 16; ++i) sv[i] = __expf(sv[i] - mrun[mf]);
      float s8[8];
#pragma unroll
      for (int i = 0; i < 8; ++i) s8[i] = sv[i] + sv[i + 8];
#pragma unroll
      for (int i = 0; i < 4; ++i) s8[i] = s8[i] + s8[i + 4];
      float sm = (s8[0] + s8[1]) + (s8[2] + s8[3]);
      sm += __shfl_xor(sm, 16, 64);
      sm += __shfl_xor(sm, 32, 64);
      lsum[mf] += sm;

#pragma unroll
      for (int jf = 0; jf < 4; ++jf) {
        bf16x4 pk;
#pragma unroll
        for (int r = 0; r < 4; ++r) pk[r] = (bf16_t)sv[jf * 4 + r];
        const int key = jf * 16 + lg * 4;
        *reinterpret_cast<bf16x4*>(
            &Ps[w * 2048 + mf * 1024 + l15 * 64 + (key ^ ((l15 & 7) << 3))]) = pk;
      }
    }
    asm volatile("s_waitcnt lgkmcnt(0)" ::: "memory");
    __builtin_amdgcn_sched_barrier(0);
    bf16x8 pfr[2][2];
#pragma unroll
    for (int mf = 0; mf < 2; ++mf)
#pragma unroll
      for (int jk = 0; jk < 2; ++jk)
        pfr[mf][jk] = *reinterpret_cast<const bf16x8*>(
            &Ps[w * 2048 + mf * 1024 + l15 * 64 + (((jk * 4 + lg) ^ (l15 & 7)) << 3)]);

    __builtin_amdgcn_s_setprio(1);
#pragma unroll
    for (int dt = 0; dt < 8; ++dt) {
      const int vrow = dt * 16 + l15;
      const int vsw = vrow & 7;
#pragma unroll
      for (int jk = 0; jk < 2; ++jk) {
        const int vc = (jk * 4 + lg) ^ vsw;
        bf16x8 vfr = *reinterpret_cast<const bf16x8*>(&Vs[vrow * 64 + vc * 8]);
#pragma unroll
        for (int mf = 0; mf < 2; ++mf)
          o[mf][dt] =
              __builtin_amdgcn_mfma_f32_16x16x32_bf16(pfr[mf][jk], vfr, o[mf][dt], 0, 0, 0);
      }
    }
    __builtin_amdgcn_s_setprio(0);
  }

  const int b = bh >> 4, h = bh & 15;
#pragma unroll
  for (int mf = 0; mf < 2; ++mf) {
    const float inv = 1.0f / lsum[mf];
    float iv[4];
#pragma unroll
    for (int r = 0; r < 4; ++r) iv[r] = __shfl(inv, lg * 4 + r, 16);
#pragma unroll
    for (int dt = 0; dt < 8; ++dt)
#pragma unroll
      for (int r = 0; r < 4; ++r) {
        const int s = q0 + mf * 16 + lg * 4 + r;
        att[((size_t)b * S_LEN + s) * 2048 + h * 128 + dt * 16 + l15] =
            (bf16_t)(o[mf][dt][r] * iv[r]);
      }
  }
}

// ---------------- host launch ----------------
extern "C" void kernel_launch(void* const* d_in, const int* in_sizes, int n_in,
                              void* d_out, int out_size, void* d_ws, size_t ws_size,
                              hipStream_t stream) {
  const float* x    = (const float*)d_in[0];
  const float* fcos = (const float*)d_in[1];
  const float* fsin = (const float*)d_in[2];
  const float* Wkv  = (const float*)d_in[3];
  const float* Wlq  = (const float*)d_in[4];
  const float* Wq   = (const float*)d_in[5];
  const float* Wk   = (const float*)d_in[6];
  const float* Wv   = (const float*)d_in[7];
  const float* Wqr  = (const float*)d_in[8];
  const float* bqr  = (const float*)d_in[9];
  const float* Wkr  = (const float*)d_in[10];
  const float* bkr  = (const float*)d_in[11];
  const float* Wo   = (const float*)d_in[12];
  const float* bo   = (const float*)d_in[13];
  float* out = (float*)d_out;

  char* ws = (char*)d_ws;
  size_t off = 0;
  auto alloc = [&](size_t bytes) {
    void* p = ws + off;
    off += (bytes + 255) & ~(size_t)255;
    return p;
  };
  bf16_t* xb    = (bf16_t*)alloc((size_t)MROWS * 2048 * 2);
  bf16_t* WcatA = (bf16_t*)alloc((size_t)3072 * 2048 * 2);  // [Wlq|Wkv|Wkr]^T, K=2048
  bf16_t* WcatB = (bf16_t*)alloc((size_t)3072 * 1536 * 2);  // [Wq|Wqr]^T,     K=1536
  bf16_t* WcatC = (bf16_t*)alloc((size_t)4096 * 512 * 2);   // [Wk|Wv]^T,      K=512
  bf16_t* WoT   = (bf16_t*)alloc((size_t)2048 * 2048 * 2);
  bf16_t* cq    = (bf16_t*)alloc((size_t)MROWS * 1536 * 2);
  bf16_t* ckv   = (bf16_t*)alloc((size_t)MROWS * 512 * 2);
  bf16_t* qfb   = (bf16_t*)alloc((size_t)NB * NH * S_LEN * DF * 2);
  bf16_t* kfb   = (bf16_t*)alloc((size_t)NB * NH * S_LEN * DF * 2);
  bf16_t* vTb   = (bf16_t*)alloc((size_t)NB * NH * HDIM * S_LEN * 2);
  bf16_t* attb  = (bf16_t*)alloc((size_t)MROWS * 2048 * 2);

  // 1. convert x
  {
    int n4 = (MROWS * 2048) / 4;
    convert_bf16<<<dim3((n4 + 255) / 256), dim3(256), 0, stream>>>(x, xb, n4);
  }
  // 2. all 8 transposes in one launch
  {
    TrPack p;
    int base = 0;
    auto set = [&](int i, const float* s, bf16_t* d, int K, int N) {
      p.d[i] = {s, d, K, N, N / 64, base};
      base += (N / 64) * (K / 64);
    };
    set(0, Wlq, WcatA, 2048, 1536);
    set(1, Wkv, WcatA + (size_t)1536 * 2048, 2048, 512);
    set(2, Wkr, WcatA + (size_t)2048 * 2048, 2048, 1024);
    set(3, Wq,  WcatB, 1536, 2048);
    set(4, Wqr, WcatB + (size_t)2048 * 1536, 1536, 1024);
    set(5, Wk,  WcatC, 512, 2048);
    set(6, Wv,  WcatC + (size_t)2048 * 512, 512, 2048);
    set(7, Wo,  WoT, 2048, 2048);
    transpose_all<<<dim3(base), dim3(256), 0, stream>>>(p);
  }

  EpiParams ep{}, ep2{};

  // 3. fused: [cq | ckv | kr-rope->kf] = xb @ WcatA^T   (N=3072, K=2048), 192 blocks
  ep = {cq, ckv, kfb, nullptr, bkr, fcos, fsin};
  gemm_8ph<5><<<dim3(192), dim3(512), 0, stream>>>(xb, WcatA, 3072, 2048, ep);
  // 4+5. fused single launch: {q,qr->qf} and {k->kf, v->vT}, 192+256 blocks
  ep  = {qfb, nullptr, nullptr, nullptr, bqr, fcos, fsin};
  ep2 = {kfb, vTb, nullptr, nullptr, nullptr, nullptr, nullptr};
  gemm_8ph67<<<dim3(448), dim3(512), 0, stream>>>(cq, WcatB, ckv, WcatC, ep, ep2);
  // 6. attention
  attn_fwd<<<dim3(512), dim3(256), 0, stream>>>(qfb, kfb, vTb, attb);
  // 7. out = att @ Wo + bo  (f32), 128 blocks
  ep = {nullptr, nullptr, nullptr, out, bo, nullptr, nullptr};
  gemm_8ph<1><<<dim3(128), dim3(512), 0, stream>>>(attb, WoT, 2048, 2048, ep);
}

// Round 15
// 345.605 us; speedup vs baseline: 1.1016x; 1.0882x over previous
//
#include <hip/hip_runtime.h>
#include <hip/hip_bf16.h>
#include <stdint.h>

#define S_LEN 2048
#define NB 2
#define NH 16
#define HDIM 128
#define RDIM 64
#define DF 192          // HDIM + RDIM
#define MROWS 4096      // NB * S_LEN

typedef __bf16 bf16_t;
typedef __attribute__((ext_vector_type(8))) __bf16 bf16x8;
typedef __attribute__((ext_vector_type(4))) __bf16 bf16x4;
typedef __attribute__((ext_vector_type(4))) float f32x4;
typedef __attribute__((ext_vector_type(4))) float float4v;

__device__ __forceinline__ void gload_lds16(const bf16_t* g, bf16_t* l) {
  __builtin_amdgcn_global_load_lds(
      (const __attribute__((address_space(1))) void*)g,
      (__attribute__((address_space(3))) void*)l, 16, 0, 0);
}

// ---------------- convert f32 -> bf16 (contiguous) ----------------
__global__ __launch_bounds__(256) void convert_bf16(const float* __restrict__ in,
                                                    bf16_t* __restrict__ out, int n4) {
  int i = blockIdx.x * 256 + threadIdx.x;
  if (i >= n4) return;
  float4v v = *reinterpret_cast<const float4v*>(&in[(size_t)i * 4]);
  bf16x4 o;
  o[0] = (bf16_t)v[0]; o[1] = (bf16_t)v[1]; o[2] = (bf16_t)v[2]; o[3] = (bf16_t)v[3];
  *reinterpret_cast<bf16x4*>(&out[(size_t)i * 4]) = o;
}

// ---------------- fused transpose: all 8 weights in one launch ----------------
struct TrDesc { const float* src; bf16_t* dst; int K; int N; int nbx; int base; };
struct TrPack { TrDesc d[8]; };

__global__ __launch_bounds__(256) void transpose_all(TrPack p) {
  __shared__ float t[64][65];
  const int bid = blockIdx.x;
  int m = 0;
#pragma unroll
  for (int i = 1; i < 8; ++i) m += (bid >= p.d[i].base);
  const TrDesc td = p.d[m];
  const int local = bid - td.base;
  const int n0 = (local % td.nbx) * 64, k0 = (local / td.nbx) * 64;
  const int tx = threadIdx.x & 63, ty = threadIdx.x >> 6;
#pragma unroll
  for (int i = ty; i < 64; i += 4)
    t[i][tx] = td.src[(size_t)(k0 + i) * td.N + n0 + tx];
  __syncthreads();
#pragma unroll
  for (int i = ty; i < 64; i += 4)
    td.dst[(size_t)(n0 + i) * td.K + k0 + tx] = (bf16_t)t[tx][i];
}

// ---------------- GEMM: 128x128, BK=32, 3-buffer, 1 barrier/tile ----------------
// 4 waves (2M x 2N), per-wave 64x64 (acc[4][4]). Combined A|B tile per buffer:
// [128 rows][8 chunks of 16B]: chunks 0-3 = A row k0..k0+31, 4-7 = B row.
// 3 buffers x 16 KB = 48 KB -> 3 blocks/CU (12 waves: cross-block overlap).
// Depth-2 prefetch; per tile: vmcnt(4) [tile t's 4 loads are 2 iters old;
// t+1's 4 stay in flight] -> ONE s_barrier -> stage(t+2 -> buf (t+2)%3,
// which all waves finished reading at iter t-1) -> 8 ds_read_b128 + 16 MFMA
// @ setprio. vmcnt(0) only on the final tile.
// Swizzle: chunk ^= row&7 (pre-swizzled global source + linear LDS dest +
// swizzled read; 2-way on read = free; verified 0-conflict pattern).
struct EpiParams {
  bf16_t* o0;
  bf16_t* o1;
  bf16_t* o2;
  float* outf;
  const float* bias;
  const float* cosb;
  const float* sinb;
};

template <int MODE>
__device__ __forceinline__ void gemm_body(const bf16_t* __restrict__ A,
                                          const bf16_t* __restrict__ Bt,
                                          int N, int K, int m0, int n0,
                                          bf16_t (*U)[128 * 64], EpiParams ep) {
  const int tid = threadIdx.x;
  const int lane = tid & 63, w = tid >> 6;    // 4 waves: 2M x 2N
  const int l15 = lane & 15, lg = lane >> 4;
  const int mw = (w >> 1) * 64, nw = (w & 1) * 64;
  const int nt = K >> 5;

  auto stage = [&](int t, int buf) {
    const int k0 = t << 5;
#pragma unroll
    for (int j = 0; j < 4; ++j) {             // 1024 slots, 4 issues x 256 thr
      const int s = j * 256 + tid;
      const int row = s >> 3, c = s & 7;
      const int cs = c ^ (row & 7);
      const bf16_t* src = (cs < 4)
          ? A + (size_t)(m0 + row) * K + k0 + cs * 8
          : Bt + (size_t)(n0 + row) * K + k0 + (cs - 4) * 8;
      gload_lds16(src, &U[buf][s * 8]);
    }
  };

  f32x4 acc[4][4] = {};
  stage(0, 0);
  stage(1, 1);                                // 8 loads in flight

  for (int t = 0; t < nt; ++t) {
    const int cur = t % 3;
    if (t + 1 < nt) {
      asm volatile("s_waitcnt vmcnt(4)" ::: "memory");  // tile t landed (2 iters old)
    } else {
      asm volatile("s_waitcnt vmcnt(0)" ::: "memory");  // final tile drain
    }
    __builtin_amdgcn_s_barrier();             // tile t visible; buf (t+2)%3 free
    __builtin_amdgcn_sched_barrier(0);
    if (t + 2 < nt) stage(t + 2, (t + 2) % 3);

    bf16x8 a[4], b[4];
#pragma unroll
    for (int i = 0; i < 4; ++i) {
      const int r = mw + i * 16 + l15;
      a[i] = *reinterpret_cast<const bf16x8*>(&U[cur][r * 64 + ((lg ^ (r & 7)) << 3)]);
    }
#pragma unroll
    for (int j = 0; j < 4; ++j) {
      const int r = nw + j * 16 + l15;
      b[j] = *reinterpret_cast<const bf16x8*>(
          &U[cur][r * 64 + (((4 + lg) ^ (r & 7)) << 3)]);
    }
    __builtin_amdgcn_s_setprio(1);
#pragma unroll
    for (int i = 0; i < 4; ++i)
#pragma unroll
      for (int j = 0; j < 4; ++j)
        acc[i][j] = __builtin_amdgcn_mfma_f32_16x16x32_bf16(a[i], b[j], acc[i][j], 0, 0, 0);
    __builtin_amdgcn_s_setprio(0);
  }

#pragma unroll
  for (int i = 0; i < 4; ++i)
#pragma unroll
    for (int j = 0; j < 4; ++j) {
      const int col = n0 + nw + j * 16 + l15;
#pragma unroll
      for (int r = 0; r < 4; ++r) {
        const int row = m0 + mw + i * 16 + lg * 4 + r;
        float v = acc[i][j][r];
        const int b = row >> 11, s = row & 2047;
        if constexpr (MODE == 1) {
          ep.outf[(size_t)row * N + col] = v + ep.bias[col];
        } else if constexpr (MODE == 5) {
          if (col < 1536) {
            ep.o0[(size_t)row * 1536 + col] = (bf16_t)v;
          } else if (col < 2048) {
            ep.o1[(size_t)row * 512 + (col - 1536)] = (bf16_t)v;
          } else {
            const int c2 = col - 2048;
            float vb = v + ep.bias[c2];
            float other = __shfl_xor(vb, 1, 64);
            const int h = c2 >> 6, dr = c2 & 63;
            const int fi = dr >> 1;
            const float c = ep.cosb[s * 32 + fi];
            const float sn = ep.sinb[s * 32 + fi];
            const float o = (c2 & 1) ? (other * sn + vb * c) : (vb * c - other * sn);
            ep.o2[(((size_t)(b * NH + h)) * S_LEN + s) * DF + 128 + dr] = (bf16_t)o;
          }
        } else if constexpr (MODE == 6) {
          if (col < 2048) {
            const int h = col >> 7, d = col & 127;
            ep.o0[(((size_t)(b * NH + h)) * S_LEN + s) * DF + d] = (bf16_t)v;
          } else {
            const int c2 = col - 2048;
            float vb = v + ep.bias[c2];
            float other = __shfl_xor(vb, 1, 64);
            const int h = c2 >> 6, dr = c2 & 63;
            const int fi = dr >> 1;
            const float c = ep.cosb[s * 32 + fi];
            const float sn = ep.sinb[s * 32 + fi];
            const float o = (c2 & 1) ? (other * sn + vb * c) : (vb * c - other * sn);
            ep.o0[(((size_t)(b * NH + h)) * S_LEN + s) * DF + 128 + dr] = (bf16_t)o;
          }
        } else {  // MODE 7
          if (col < 2048) {
            const int h = col >> 7, d = col & 127;
            ep.o0[(((size_t)(b * NH + h)) * S_LEN + s) * DF + d] = (bf16_t)v;
          } else {
            const int c2 = col - 2048;
            const int h = c2 >> 7, d = c2 & 127;
            ep.o1[(((size_t)(b * NH + h)) * HDIM + d) * S_LEN + s] = (bf16_t)v;
          }
        }
      }
    }
}

template <int MODE>
__global__ __launch_bounds__(256, 3) void gemm_3b(const bf16_t* __restrict__ A,
                                                  const bf16_t* __restrict__ Bt,
                                                  int N, int K, EpiParams ep) {
  __shared__ alignas(16) bf16_t U[3][128 * 64];   // 48 KB
  const int nwg = gridDim.x;
  int f = blockIdx.x;
  f = (f & 7) * (nwg >> 3) + (f >> 3);        // T1 XCD swizzle (nwg % 8 == 0)
  const int nbx = N >> 7;
  const int m0 = (f / nbx) * 128, n0 = (f % nbx) * 128;
  gemm_body<MODE>(A, Bt, N, K, m0, n0, U, ep);
}

// Fused: blocks [0,768) MODE 6 (N=3072,K=1536); [768,1792) MODE 7 (N=4096,K=512).
__global__ __launch_bounds__(256, 3) void gemm_3b67(const bf16_t* __restrict__ A6,
                                                    const bf16_t* __restrict__ Bt6,
                                                    const bf16_t* __restrict__ A7,
                                                    const bf16_t* __restrict__ Bt7,
                                                    EpiParams ep6, EpiParams ep7) {
  __shared__ alignas(16) bf16_t U[3][128 * 64];
  const int bid = blockIdx.x;
  if (bid < 768) {
    int f = (bid & 7) * 96 + (bid >> 3);
    const int m0 = (f / 24) * 128, n0 = (f % 24) * 128;
    gemm_body<6>(A6, Bt6, 3072, 1536, m0, n0, U, ep6);
  } else {
    int b2 = bid - 768;
    int f = (b2 & 7) * 128 + (b2 >> 3);
    const int m0 = (f / 32) * 128, n0 = (f % 32) * 128;
    gemm_body<7>(A7, Bt7, 4096, 512, m0, n0, U, ep7);
  }
}

// ---------------- flash attention (causal), swapped softmax, 32q/wave ----------------
// (unchanged from r8/r10: 4 waves x 32 q-rows, swapped QK^T, defer-max, 56 KB LDS)
__global__ __launch_bounds__(256, 2) void attn_fwd(const bf16_t* __restrict__ qf,
                                                   const bf16_t* __restrict__ kf,
                                                   const bf16_t* __restrict__ vT,
                                                   bf16_t* __restrict__ att) {
  const int tid = threadIdx.x;
  const int lane = tid & 63, w = tid >> 6;   // w: 0..3
  const int l15 = lane & 15, lg = lane >> 4;
  const int l = blockIdx.x;                  // 0..511
  const int bh = (l & 7) * 4 + ((l >> 3) & 3);
  const int qchunk = l >> 5;                 // 0..15
  const int qb0 = (15 - qchunk) * 128;
  const int q0 = qb0 + w * 32;
  const float scale = 0.07216878364870322f;  // 1/sqrt(192)

  __shared__ alignas(16) bf16_t Ks[64 * 192];
  __shared__ alignas(16) bf16_t Vs[128 * 64];
  __shared__ alignas(16) bf16_t Ps[4 * 2048];

  bf16x8 qfr[2][6];
#pragma unroll
  for (int mf = 0; mf < 2; ++mf) {
    const bf16_t* qptr = qf + ((size_t)bh * S_LEN + q0 + mf * 16 + l15) * DF + lg * 8;
#pragma unroll
    for (int d = 0; d < 6; ++d)
      qfr[mf][d] = *reinterpret_cast<const bf16x8*>(qptr + d * 32);
  }

  f32x4 o[2][8] = {};
  float mrun[2] = {-1e30f, -1e30f}, lsum[2] = {0.0f, 0.0f};

  const bf16_t* kb0 = kf + (size_t)bh * S_LEN * DF;
  const bf16_t* vb0 = vT + (size_t)bh * HDIM * S_LEN;
  const int njt = qb0 / 64 + 2;
  const int wslot = tid & ~63;

  for (int jt = 0; jt < njt; ++jt) {
    const int j0 = jt * 64;
    __syncthreads();
    const bf16_t* kTile = kb0 + (size_t)j0 * DF;
#pragma unroll
    for (int i = 0; i < 6; ++i) {
      const int s = i * 256 + tid;
      const int row = s / 24;
      const int c = s - row * 24;
      const int cs = c ^ (row & 7);
      gload_lds16(kTile + (size_t)row * DF + cs * 8,
                  Ks + (size_t)(i * 256 + wslot) * 8);
    }
    const bf16_t* vTile = vb0 + j0;
#pragma unroll
    for (int i = 0; i < 4; ++i) {
      const int s = i * 256 + tid;
      const int row = s >> 3;
      const int c = s & 7;
      const int cs = c ^ (row & 7);
      gload_lds16(vTile + (size_t)row * S_LEN + cs * 8,
                  Vs + (size_t)(i * 256 + wslot) * 8);
    }
    __syncthreads();

    if (j0 > q0 + 31) continue;

    f32x4 sa[2][4] = {};
    __builtin_amdgcn_s_setprio(1);
#pragma unroll
    for (int jf = 0; jf < 4; ++jf) {
      const int krow = jf * 16 + l15;
      const int ksw = krow & 7;
#pragma unroll
      for (int d = 0; d < 6; ++d) {
        const int kc = (4 * d + lg) ^ ksw;
        bf16x8 kfr = *reinterpret_cast<const bf16x8*>(&Ks[krow * 192 + kc * 8]);
#pragma unroll
        for (int mf = 0; mf < 2; ++mf)
          sa[mf][jf] =
              __builtin_amdgcn_mfma_f32_16x16x32_bf16(kfr, qfr[mf][d], sa[mf][jf], 0, 0, 0);
      }
    }
    __builtin_amdgcn_s_setprio(0);

#pragma unroll
    for (int mf = 0; mf < 2; ++mf) {
      const int qi = q0 + mf * 16 + l15;
      const bool full = (j0 + 63 <= q0 + mf * 16);
      float sv[16];
#pragma unroll
      for (int jf = 0; jf < 4; ++jf)
#pragma unroll
        for (int r = 0; r < 4; ++r) {
          float x = sa[mf][jf][r] * scale;
          if (!full) {
            const int j = j0 + jf * 16 + lg * 4 + r;
            if (j > qi) x = -1e30f;
          }
          sv[jf * 4 + r] = x;
        }

      float a8[8];
#pragma unroll
      for (int i = 0; i < 8; ++i) a8[i] = fmaxf(sv[i], sv[i + 8]);
#pragma unroll
      for (int i = 0; i < 4; ++i) a8[i] = fmaxf(a8[i], a8[i + 4]);
      float mx = fmaxf(fmaxf(a8[0], a8[1]), fmaxf(a8[2], a8[3]));
      mx = fmaxf(mx, __shfl_xor(mx, 16, 64));
      mx = fmaxf(mx, __shfl_xor(mx, 32, 64));

      if (__any(mx > mrun[mf] + 8.0f)) {
        const float mn = fmaxf(mrun[mf], mx);
        const float alpha = __expf(mrun[mf] - mn);
        mrun[mf] = mn;
        lsum[mf] *= alpha;
        float af[4];
#pragma unroll
        for (int r = 0; r < 4; ++r) af[r] = __shfl(alpha, lg * 4 + r, 16);
#pragma unroll
        for (int dt = 0; dt < 8; ++dt)
#pragma unroll
          for (int r = 0; r < 4; ++r) o[mf][dt][r] *= af[r];
      }

#pragma unroll
      for (int i = 0; i < 16; ++i) sv[i] = __expf(sv[i] - mrun[mf]);
      float s8[8];
#pragma unroll
      for (int i = 0; i < 8; ++i) s8[i] = sv[i] + sv[i + 8];
#pragma unroll
      for (int i = 0; i < 4; ++i) s8[i] = s8[i] + s8[i + 4];
      float sm = (s8[0] + s8[1]) + (s8[2] + s8[3]);
      sm += __shfl_xor(sm, 16, 64);
      sm += __shfl_xor(sm, 32, 64);
      lsum[mf] += sm;

#pragma unroll
      for (int jf = 0; jf < 4; ++jf) {
        bf16x4 pk;
#pragma unroll
        for (int r = 0; r < 4; ++r) pk[r] = (bf16_t)sv[jf * 4 + r];
        const int key = jf * 16 + lg * 4;
        *reinterpret_cast<bf16x4*>(
            &Ps[w * 2048 + mf * 1024 + l15 * 64 + (key ^ ((l15 & 7) << 3))]) = pk;
      }
    }
    asm volatile("s_waitcnt lgkmcnt(0)" ::: "memory");
    __builtin_amdgcn_sched_barrier(0);
    bf16x8 pfr[2][2];
#pragma unroll
    for (int mf = 0; mf < 2; ++mf)
#pragma unroll
      for (int jk = 0; jk < 2; ++jk)
        pfr[mf][jk] = *reinterpret_cast<const bf16x8*>(
            &Ps[w * 2048 + mf * 1024 + l15 * 64 + (((jk * 4 + lg) ^ (l15 & 7)) << 3)]);

    __builtin_amdgcn_s_setprio(1);
#pragma unroll
    for (int dt = 0; dt < 8; ++dt) {
      const int vrow = dt * 16 + l15;
      const int vsw = vrow & 7;
#pragma unroll
      for (int jk = 0; jk < 2; ++jk) {
        const int vc = (jk * 4 + lg) ^ vsw;
        bf16x8 vfr = *reinterpret_cast<const bf16x8*>(&Vs[vrow * 64 + vc * 8]);
#pragma unroll
        for (int mf = 0; mf < 2; ++mf)
          o[mf][dt] =
              __builtin_amdgcn_mfma_f32_16x16x32_bf16(pfr[mf][jk], vfr, o[mf][dt], 0, 0, 0);
      }
    }
    __builtin_amdgcn_s_setprio(0);
  }

  const int b = bh >> 4, h = bh & 15;
#pragma unroll
  for (int mf = 0; mf < 2; ++mf) {
    const float inv = 1.0f / lsum[mf];
    float iv[4];
#pragma unroll
    for (int r = 0; r < 4; ++r) iv[r] = __shfl(inv, lg * 4 + r, 16);
#pragma unroll
    for (int dt = 0; dt < 8; ++dt)
#pragma unroll
      for (int r = 0; r < 4; ++r) {
        const int s = q0 + mf * 16 + lg * 4 + r;
        att[((size_t)b * S_LEN + s) * 2048 + h * 128 + dt * 16 + l15] =
            (bf16_t)(o[mf][dt][r] * iv[r]);
      }
  }
}

// ---------------- host launch ----------------
extern "C" void kernel_launch(void* const* d_in, const int* in_sizes, int n_in,
                              void* d_out, int out_size, void* d_ws, size_t ws_size,
                              hipStream_t stream) {
  const float* x    = (const float*)d_in[0];
  const float* fcos = (const float*)d_in[1];
  const float* fsin = (const float*)d_in[2];
  const float* Wkv  = (const float*)d_in[3];
  const float* Wlq  = (const float*)d_in[4];
  const float* Wq   = (const float*)d_in[5];
  const float* Wk   = (const float*)d_in[6];
  const float* Wv   = (const float*)d_in[7];
  const float* Wqr  = (const float*)d_in[8];
  const float* bqr  = (const float*)d_in[9];
  const float* Wkr  = (const float*)d_in[10];
  const float* bkr  = (const float*)d_in[11];
  const float* Wo   = (const float*)d_in[12];
  const float* bo   = (const float*)d_in[13];
  float* out = (float*)d_out;

  char* ws = (char*)d_ws;
  size_t off = 0;
  auto alloc = [&](size_t bytes) {
    void* p = ws + off;
    off += (bytes + 255) & ~(size_t)255;
    return p;
  };
  bf16_t* xb    = (bf16_t*)alloc((size_t)MROWS * 2048 * 2);
  bf16_t* WcatA = (bf16_t*)alloc((size_t)3072 * 2048 * 2);  // [Wlq|Wkv|Wkr]^T, K=2048
  bf16_t* WcatB = (bf16_t*)alloc((size_t)3072 * 1536 * 2);  // [Wq|Wqr]^T,     K=1536
  bf16_t* WcatC = (bf16_t*)alloc((size_t)4096 * 512 * 2);   // [Wk|Wv]^T,      K=512
  bf16_t* WoT   = (bf16_t*)alloc((size_t)2048 * 2048 * 2);
  bf16_t* cq    = (bf16_t*)alloc((size_t)MROWS * 1536 * 2);
  bf16_t* ckv   = (bf16_t*)alloc((size_t)MROWS * 512 * 2);
  bf16_t* qfb   = (bf16_t*)alloc((size_t)NB * NH * S_LEN * DF * 2);
  bf16_t* kfb   = (bf16_t*)alloc((size_t)NB * NH * S_LEN * DF * 2);
  bf16_t* vTb   = (bf16_t*)alloc((size_t)NB * NH * HDIM * S_LEN * 2);
  bf16_t* attb  = (bf16_t*)alloc((size_t)MROWS * 2048 * 2);

  // 1. convert x
  {
    int n4 = (MROWS * 2048) / 4;
    convert_bf16<<<dim3((n4 + 255) / 256), dim3(256), 0, stream>>>(x, xb, n4);
  }
  // 2. all 8 transposes in one launch
  {
    TrPack p;
    int base = 0;
    auto set = [&](int i, const float* s, bf16_t* d, int K, int N) {
      p.d[i] = {s, d, K, N, N / 64, base};
      base += (N / 64) * (K / 64);
    };
    set(0, Wlq, WcatA, 2048, 1536);
    set(1, Wkv, WcatA + (size_t)1536 * 2048, 2048, 512);
    set(2, Wkr, WcatA + (size_t)2048 * 2048, 2048, 1024);
    set(3, Wq,  WcatB, 1536, 2048);
    set(4, Wqr, WcatB + (size_t)2048 * 1536, 1536, 1024);
    set(5, Wk,  WcatC, 512, 2048);
    set(6, Wv,  WcatC + (size_t)2048 * 512, 512, 2048);
    set(7, Wo,  WoT, 2048, 2048);
    transpose_all<<<dim3(base), dim3(256), 0, stream>>>(p);
  }

  EpiParams ep{}, ep2{};

  // 3. fused: [cq | ckv | kr-rope->kf] = xb @ WcatA^T   (N=3072, K=2048), 768 blocks
  ep = {cq, ckv, kfb, nullptr, bkr, fcos, fsin};
  gemm_3b<5><<<dim3(768), dim3(256), 0, stream>>>(xb, WcatA, 3072, 2048, ep);
  // 4+5. fused single launch: {q,qr->qf} and {k->kf, v->vT}, 768+1024 blocks
  ep  = {qfb, nullptr, nullptr, nullptr, bqr, fcos, fsin};
  ep2 = {kfb, vTb, nullptr, nullptr, nullptr, nullptr, nullptr};
  gemm_3b67<<<dim3(1792), dim3(256), 0, stream>>>(cq, WcatB, ckv, WcatC, ep, ep2);
  // 6. attention
  attn_fwd<<<dim3(512), dim3(256), 0, stream>>>(qfb, kfb, vTb, attb);
  // 7. out = att @ Wo + bo  (f32), 512 blocks
  ep = {nullptr, nullptr, nullptr, out, bo, nullptr, nullptr};
  gemm_3b<1><<<dim3(512), dim3(256), 0, stream>>>(attb, WoT, 2048, 2048, ep);
}

// Round 16
// 344.475 us; speedup vs baseline: 1.1052x; 1.0033x over previous
//
#include <hip/hip_runtime.h>
#include <hip/hip_bf16.h>
#include <stdint.h>

#define S_LEN 2048
#define NB 2
#define NH 16
#define HDIM 128
#define RDIM 64
#define DF 192          // HDIM + RDIM
#define MROWS 4096      // NB * S_LEN

typedef __bf16 bf16_t;
typedef __attribute__((ext_vector_type(8))) __bf16 bf16x8;
typedef __attribute__((ext_vector_type(4))) __bf16 bf16x4;
typedef __attribute__((ext_vector_type(4))) float f32x4;
typedef __attribute__((ext_vector_type(4))) float float4v;

__device__ __forceinline__ void gload_lds16(const bf16_t* g, bf16_t* l) {
  __builtin_amdgcn_global_load_lds(
      (const __attribute__((address_space(1))) void*)g,
      (__attribute__((address_space(3))) void*)l, 16, 0, 0);
}

// ---------------- fused prep: convert x (f32->bf16) + all 8 weight transposes ----
// Blocks [0, convBlocks): contiguous convert (256 thr x 4 f32).
// Blocks [convBlocks, convBlocks+trBlocks): 64x64 transpose tiles.
struct TrDesc { const float* src; bf16_t* dst; int K; int N; int nbx; int base; };
struct PrepPack {
  const float* x; bf16_t* xb; int n4; int convBlocks;
  TrDesc d[8];
};

__global__ __launch_bounds__(256) void prep_all(PrepPack p) {
  __shared__ float t[64][65];
  const int bid = blockIdx.x;
  if (bid < p.convBlocks) {
    int i = bid * 256 + threadIdx.x;
    if (i >= p.n4) return;
    float4v v = *reinterpret_cast<const float4v*>(&p.x[(size_t)i * 4]);
    bf16x4 o;
    o[0] = (bf16_t)v[0]; o[1] = (bf16_t)v[1]; o[2] = (bf16_t)v[2]; o[3] = (bf16_t)v[3];
    *reinterpret_cast<bf16x4*>(&p.xb[(size_t)i * 4]) = o;
    return;
  }
  const int tb = bid - p.convBlocks;
  int m = 0;
#pragma unroll
  for (int i = 1; i < 8; ++i) m += (tb >= p.d[i].base);
  const TrDesc td = p.d[m];
  const int local = tb - td.base;
  const int n0 = (local % td.nbx) * 64, k0 = (local / td.nbx) * 64;
  const int tx = threadIdx.x & 63, ty = threadIdx.x >> 6;
#pragma unroll
  for (int i = ty; i < 64; i += 4)
    t[i][tx] = td.src[(size_t)(k0 + i) * td.N + n0 + tx];
  __syncthreads();
#pragma unroll
  for (int i = ty; i < 64; i += 4)
    td.dst[(size_t)(n0 + i) * td.K + k0 + tx] = (bf16_t)t[tx][i];
}

// ---------------- GEMM: 128x128 tile, BK=64, double-buffered, counted vmcnt ----
// (r10's exact skeleton — best measured variant: 105.5 us / 2.0 TB/s on gemm67)
// 4 waves (256 thr), per-wave 64x64 (acc[4][4]). LDS 64KB -> 2 blocks/CU.
//   bar1 (buf^1 free) -> stage(t+1 -> buf^1) -> vmcnt(8) -> bar2 -> 32 MFMA.
// A/B tiles XOR-swizzled (16B chunk ^= row&7): pre-swizzled GLOBAL source +
// linear LDS dest + swizzled read (verified 0-conflict).
struct EpiParams {
  bf16_t* o0;
  bf16_t* o1;
  bf16_t* o2;
  float* outf;
  const float* bias;
  const float* cosb;
  const float* sinb;
};

template <int MODE>
__device__ __forceinline__ void gemm_body(const bf16_t* __restrict__ A,
                                          const bf16_t* __restrict__ Bt,
                                          int N, int K, int m0, int n0,
                                          bf16_t (*Ab)[128 * 64],
                                          bf16_t (*Bb)[128 * 64], EpiParams ep) {
  const int tid = threadIdx.x;
  const int lane = tid & 63, w = tid >> 6;    // 4 waves: 2M x 2N
  const int l15 = lane & 15, lg = lane >> 4;
  const int mw = (w >> 1) * 64, nw = (w & 1) * 64;
  const int nt = K >> 6;

  auto stage = [&](int t, int buf) {
    const int k0 = t << 6;
#pragma unroll
    for (int j = 0; j < 4; ++j) {             // A: 128 rows x 8 chunks = 1024 slots
      const int s = j * 256 + tid;
      const int row = s >> 3, c = s & 7;
      const int cs = c ^ (row & 7);
      gload_lds16(A + (size_t)(m0 + row) * K + k0 + cs * 8, &Ab[buf][s * 8]);
    }
#pragma unroll
    for (int j = 0; j < 4; ++j) {             // B: 128 rows x 8 chunks = 1024 slots
      const int s = j * 256 + tid;
      const int row = s >> 3, c = s & 7;
      const int cs = c ^ (row & 7);
      gload_lds16(Bt + (size_t)(n0 + row) * K + k0 + cs * 8, &Bb[buf][s * 8]);
    }
  };

  f32x4 acc[4][4] = {};
  stage(0, 0);                                // prologue: 8 loads in flight

  for (int t = 0; t < nt; ++t) {
    const int cur = t & 1;
    __builtin_amdgcn_s_barrier();             // all waves done compute(t-1) -> buf^1 free
    if (t + 1 < nt) {
      stage(t + 1, cur ^ 1);
      asm volatile("s_waitcnt vmcnt(8)" ::: "memory");  // own tile-t loads landed
    } else {
      asm volatile("s_waitcnt vmcnt(0)" ::: "memory");  // final tile drain
    }
    __builtin_amdgcn_s_barrier();             // every wave's tile-t loads landed
    __builtin_amdgcn_sched_barrier(0);

    __builtin_amdgcn_s_setprio(1);
#pragma unroll
    for (int kk = 0; kk < 2; ++kk) {
      const int c = kk * 4 + lg;
      bf16x8 a[4], b[4];
#pragma unroll
      for (int i = 0; i < 4; ++i) {
        const int r = mw + i * 16 + l15;
        a[i] = *reinterpret_cast<const bf16x8*>(&Ab[cur][r * 64 + ((c ^ (r & 7)) << 3)]);
      }
#pragma unroll
      for (int j = 0; j < 4; ++j) {
        const int r = nw + j * 16 + l15;
        b[j] = *reinterpret_cast<const bf16x8*>(&Bb[cur][r * 64 + ((c ^ (r & 7)) << 3)]);
      }
#pragma unroll
      for (int i = 0; i < 4; ++i)
#pragma unroll
        for (int j = 0; j < 4; ++j)
          acc[i][j] = __builtin_amdgcn_mfma_f32_16x16x32_bf16(a[i], b[j], acc[i][j], 0, 0, 0);
    }
    __builtin_amdgcn_s_setprio(0);
  }

#pragma unroll
  for (int i = 0; i < 4; ++i)
#pragma unroll
    for (int j = 0; j < 4; ++j) {
      const int col = n0 + nw + j * 16 + l15;
#pragma unroll
      for (int r = 0; r < 4; ++r) {
        const int row = m0 + mw + i * 16 + lg * 4 + r;
        float v = acc[i][j][r];
        const int b = row >> 11, s = row & 2047;
        if constexpr (MODE == 1) {
          ep.outf[(size_t)row * N + col] = v + ep.bias[col];
        } else if constexpr (MODE == 5) {
          if (col < 1536) {
            ep.o0[(size_t)row * 1536 + col] = (bf16_t)v;
          } else if (col < 2048) {
            ep.o1[(size_t)row * 512 + (col - 1536)] = (bf16_t)v;
          } else {
            const int c2 = col - 2048;
            float vb = v + ep.bias[c2];
            float other = __shfl_xor(vb, 1, 64);
            const int h = c2 >> 6, dr = c2 & 63;
            const int fi = dr >> 1;
            const float c = ep.cosb[s * 32 + fi];
            const float sn = ep.sinb[s * 32 + fi];
            const float o = (c2 & 1) ? (other * sn + vb * c) : (vb * c - other * sn);
            ep.o2[(((size_t)(b * NH + h)) * S_LEN + s) * DF + 128 + dr] = (bf16_t)o;
          }
        } else if constexpr (MODE == 6) {
          if (col < 2048) {
            const int h = col >> 7, d = col & 127;
            ep.o0[(((size_t)(b * NH + h)) * S_LEN + s) * DF + d] = (bf16_t)v;
          } else {
            const int c2 = col - 2048;
            float vb = v + ep.bias[c2];
            float other = __shfl_xor(vb, 1, 64);
            const int h = c2 >> 6, dr = c2 & 63;
            const int fi = dr >> 1;
            const float c = ep.cosb[s * 32 + fi];
            const float sn = ep.sinb[s * 32 + fi];
            const float o = (c2 & 1) ? (other * sn + vb * c) : (vb * c - other * sn);
            ep.o0[(((size_t)(b * NH + h)) * S_LEN + s) * DF + 128 + dr] = (bf16_t)o;
          }
        } else {  // MODE 7
          if (col < 2048) {
            const int h = col >> 7, d = col & 127;
            ep.o0[(((size_t)(b * NH + h)) * S_LEN + s) * DF + d] = (bf16_t)v;
          } else {
            const int c2 = col - 2048;
            const int h = c2 >> 7, d = c2 & 127;
            ep.o1[(((size_t)(b * NH + h)) * HDIM + d) * S_LEN + s] = (bf16_t)v;
          }
        }
      }
    }
}

template <int MODE>
__global__ __launch_bounds__(256, 2) void gemm_db(const bf16_t* __restrict__ A,
                                                  const bf16_t* __restrict__ Bt,
                                                  int N, int K, EpiParams ep) {
  __shared__ alignas(16) bf16_t Ab[2][128 * 64];
  __shared__ alignas(16) bf16_t Bb[2][128 * 64];
  const int nwg = gridDim.x;
  int f = blockIdx.x;
  f = (f & 7) * (nwg >> 3) + (f >> 3);        // T1 XCD swizzle (nwg % 8 == 0)
  const int nbx = N >> 7;
  const int m0 = (f / nbx) * 128, n0 = (f % nbx) * 128;
  gemm_body<MODE>(A, Bt, N, K, m0, n0, Ab, Bb, ep);
}

// Fused: blocks [0,768) MODE 6 (N=3072,K=1536); [768,1792) MODE 7 (N=4096,K=512).
__global__ __launch_bounds__(256, 2) void gemm_db67(const bf16_t* __restrict__ A6,
                                                    const bf16_t* __restrict__ Bt6,
                                                    const bf16_t* __restrict__ A7,
                                                    const bf16_t* __restrict__ Bt7,
                                                    EpiParams ep6, EpiParams ep7) {
  __shared__ alignas(16) bf16_t Ab[2][128 * 64];
  __shared__ alignas(16) bf16_t Bb[2][128 * 64];
  const int bid = blockIdx.x;
  if (bid < 768) {
    int f = (bid & 7) * 96 + (bid >> 3);
    const int m0 = (f / 24) * 128, n0 = (f % 24) * 128;
    gemm_body<6>(A6, Bt6, 3072, 1536, m0, n0, Ab, Bb, ep6);
  } else {
    int b2 = bid - 768;
    int f = (b2 & 7) * 128 + (b2 >> 3);
    const int m0 = (f / 32) * 128, n0 = (f % 32) * 128;
    gemm_body<7>(A7, Bt7, 4096, 512, m0, n0, Ab, Bb, ep7);
  }
}

// ---------------- flash attention (causal), swapped softmax, 32q/wave ----------------
// (unchanged: 4 waves x 32 q-rows, swapped QK^T, defer-max, 56 KB LDS)
__global__ __launch_bounds__(256, 2) void attn_fwd(const bf16_t* __restrict__ qf,
                                                   const bf16_t* __restrict__ kf,
                                                   const bf16_t* __restrict__ vT,
                                                   bf16_t* __restrict__ att) {
  const int tid = threadIdx.x;
  const int lane = tid & 63, w = tid >> 6;   // w: 0..3
  const int l15 = lane & 15, lg = lane >> 4;
  const int l = blockIdx.x;                  // 0..511
  const int bh = (l & 7) * 4 + ((l >> 3) & 3);
  const int qchunk = l >> 5;                 // 0..15
  const int qb0 = (15 - qchunk) * 128;
  const int q0 = qb0 + w * 32;
  const float scale = 0.07216878364870322f;  // 1/sqrt(192)

  __shared__ alignas(16) bf16_t Ks[64 * 192];
  __shared__ alignas(16) bf16_t Vs[128 * 64];
  __shared__ alignas(16) bf16_t Ps[4 * 2048];

  bf16x8 qfr[2][6];
#pragma unroll
  for (int mf = 0; mf < 2; ++mf) {
    const bf16_t* qptr = qf + ((size_t)bh * S_LEN + q0 + mf * 16 + l15) * DF + lg * 8;
#pragma unroll
    for (int d = 0; d < 6; ++d)
      qfr[mf][d] = *reinterpret_cast<const bf16x8*>(qptr + d * 32);
  }

  f32x4 o[2][8] = {};
  float mrun[2] = {-1e30f, -1e30f}, lsum[2] = {0.0f, 0.0f};

  const bf16_t* kb0 = kf + (size_t)bh * S_LEN * DF;
  const bf16_t* vb0 = vT + (size_t)bh * HDIM * S_LEN;
  const int njt = qb0 / 64 + 2;
  const int wslot = tid & ~63;

  for (int jt = 0; jt < njt; ++jt) {
    const int j0 = jt * 64;
    __syncthreads();
    const bf16_t* kTile = kb0 + (size_t)j0 * DF;
#pragma unroll
    for (int i = 0; i < 6; ++i) {
      const int s = i * 256 + tid;
      const int row = s / 24;
      const int c = s - row * 24;
      const int cs = c ^ (row & 7);
      gload_lds16(kTile + (size_t)row * DF + cs * 8,
                  Ks + (size_t)(i * 256 + wslot) * 8);
    }
    const bf16_t* vTile = vb0 + j0;
#pragma unroll
    for (int i = 0; i < 4; ++i) {
      const int s = i * 256 + tid;
      const int row = s >> 3;
      const int c = s & 7;
      const int cs = c ^ (row & 7);
      gload_lds16(vTile + (size_t)row * S_LEN + cs * 8,
                  Vs + (size_t)(i * 256 + wslot) * 8);
    }
    __syncthreads();

    if (j0 > q0 + 31) continue;

    f32x4 sa[2][4] = {};
    __builtin_amdgcn_s_setprio(1);
#pragma unroll
    for (int jf = 0; jf < 4; ++jf) {
      const int krow = jf * 16 + l15;
      const int ksw = krow & 7;
#pragma unroll
      for (int d = 0; d < 6; ++d) {
        const int kc = (4 * d + lg) ^ ksw;
        bf16x8 kfr = *reinterpret_cast<const bf16x8*>(&Ks[krow * 192 + kc * 8]);
#pragma unroll
        for (int mf = 0; mf < 2; ++mf)
          sa[mf][jf] =
              __builtin_amdgcn_mfma_f32_16x16x32_bf16(kfr, qfr[mf][d], sa[mf][jf], 0, 0, 0);
      }
    }
    __builtin_amdgcn_s_setprio(0);

#pragma unroll
    for (int mf = 0; mf < 2; ++mf) {
      const int qi = q0 + mf * 16 + l15;
      const bool full = (j0 + 63 <= q0 + mf * 16);
      float sv[16];
#pragma unroll
      for (int jf = 0; jf < 4; ++jf)
#pragma unroll
        for (int r = 0; r < 4; ++r) {
          float x = sa[mf][jf][r] * scale;
          if (!full) {
            const int j = j0 + jf * 16 + lg * 4 + r;
            if (j > qi) x = -1e30f;
          }
          sv[jf * 4 + r] = x;
        }

      float a8[8];
#pragma unroll
      for (int i = 0; i < 8; ++i) a8[i] = fmaxf(sv[i], sv[i + 8]);
#pragma unroll
      for (int i = 0; i < 4; ++i) a8[i] = fmaxf(a8[i], a8[i + 4]);
      float mx = fmaxf(fmaxf(a8[0], a8[1]), fmaxf(a8[2], a8[3]));
      mx = fmaxf(mx, __shfl_xor(mx, 16, 64));
      mx = fmaxf(mx, __shfl_xor(mx, 32, 64));

      if (__any(mx > mrun[mf] + 8.0f)) {
        const float mn = fmaxf(mrun[mf], mx);
        const float alpha = __expf(mrun[mf] - mn);
        mrun[mf] = mn;
        lsum[mf] *= alpha;
        float af[4];
#pragma unroll
        for (int r = 0; r < 4; ++r) af[r] = __shfl(alpha, lg * 4 + r, 16);
#pragma unroll
        for (int dt = 0; dt < 8; ++dt)
#pragma unroll
          for (int r = 0; r < 4; ++r) o[mf][dt][r] *= af[r];
      }

#pragma unroll
      for (int i = 0; i < 16; ++i) sv[i] = __expf(sv[i] - mrun[mf]);
      float s8[8];
#pragma unroll
      for (int i = 0; i < 8; ++i) s8[i] = sv[i] + sv[i + 8];
#pragma unroll
      for (int i = 0; i < 4; ++i) s8[i] = s8[i] + s8[i + 4];
      float sm = (s8[0] + s8[1]) + (s8[2] + s8[3]);
      sm += __shfl_xor(sm, 16, 64);
      sm += __shfl_xor(sm, 32, 64);
      lsum[mf] += sm;

#pragma unroll
      for (int jf = 0; jf < 4; ++jf) {
        bf16x4 pk;
#pragma unroll
        for (int r = 0; r < 4; ++r) pk[r] = (bf16_t)sv[jf * 4 + r];
        const int key = jf * 16 + lg * 4;
        *reinterpret_cast<bf16x4*>(
            &Ps[w * 2048 + mf * 1024 + l15 * 64 + (key ^ ((l15 & 7) << 3))]) = pk;
      }
    }
    asm volatile("s_waitcnt lgkmcnt(0)" ::: "memory");
    __builtin_amdgcn_sched_barrier(0);
    bf16x8 pfr[2][2];
#pragma unroll
    for (int mf = 0; mf < 2; ++mf)
#pragma unroll
      for (int jk = 0; jk < 2; ++jk)
        pfr[mf][jk] = *reinterpret_cast<const bf16x8*>(
            &Ps[w * 2048 + mf * 1024 + l15 * 64 + (((jk * 4 + lg) ^ (l15 & 7)) << 3)]);

    __builtin_amdgcn_s_setprio(1);
#pragma unroll
    for (int dt = 0; dt < 8; ++dt) {
      const int vrow = dt * 16 + l15;
      const int vsw = vrow & 7;
#pragma unroll
      for (int jk = 0; jk < 2; ++jk) {
        const int vc = (jk * 4 + lg) ^ vsw;
        bf16x8 vfr = *reinterpret_cast<const bf16x8*>(&Vs[vrow * 64 + vc * 8]);
#pragma unroll
        for (int mf = 0; mf < 2; ++mf)
          o[mf][dt] =
              __builtin_amdgcn_mfma_f32_16x16x32_bf16(pfr[mf][jk], vfr, o[mf][dt], 0, 0, 0);
      }
    }
    __builtin_amdgcn_s_setprio(0);
  }

  const int b = bh >> 4, h = bh & 15;
#pragma unroll
  for (int mf = 0; mf < 2; ++mf) {
    const float inv = 1.0f / lsum[mf];
    float iv[4];
#pragma unroll
    for (int r = 0; r < 4; ++r) iv[r] = __shfl(inv, lg * 4 + r, 16);
#pragma unroll
    for (int dt = 0; dt < 8; ++dt)
#pragma unroll
      for (int r = 0; r < 4; ++r) {
        const int s = q0 + mf * 16 + lg * 4 + r;
        att[((size_t)b * S_LEN + s) * 2048 + h * 128 + dt * 16 + l15] =
            (bf16_t)(o[mf][dt][r] * iv[r]);
      }
  }
}

// ---------------- host launch ----------------
extern "C" void kernel_launch(void* const* d_in, const int* in_sizes, int n_in,
                              void* d_out, int out_size, void* d_ws, size_t ws_size,
                              hipStream_t stream) {
  const float* x    = (const float*)d_in[0];
  const float* fcos = (const float*)d_in[1];
  const float* fsin = (const float*)d_in[2];
  const float* Wkv  = (const float*)d_in[3];
  const float* Wlq  = (const float*)d_in[4];
  const float* Wq   = (const float*)d_in[5];
  const float* Wk   = (const float*)d_in[6];
  const float* Wv   = (const float*)d_in[7];
  const float* Wqr  = (const float*)d_in[8];
  const float* bqr  = (const float*)d_in[9];
  const float* Wkr  = (const float*)d_in[10];
  const float* bkr  = (const float*)d_in[11];
  const float* Wo   = (const float*)d_in[12];
  const float* bo   = (const float*)d_in[13];
  float* out = (float*)d_out;

  char* ws = (char*)d_ws;
  size_t off = 0;
  auto alloc = [&](size_t bytes) {
    void* p = ws + off;
    off += (bytes + 255) & ~(size_t)255;
    return p;
  };
  bf16_t* xb    = (bf16_t*)alloc((size_t)MROWS * 2048 * 2);
  bf16_t* WcatA = (bf16_t*)alloc((size_t)3072 * 2048 * 2);  // [Wlq|Wkv|Wkr]^T, K=2048
  bf16_t* WcatB = (bf16_t*)alloc((size_t)3072 * 1536 * 2);  // [Wq|Wqr]^T,     K=1536
  bf16_t* WcatC = (bf16_t*)alloc((size_t)4096 * 512 * 2);   // [Wk|Wv]^T,      K=512
  bf16_t* WoT   = (bf16_t*)alloc((size_t)2048 * 2048 * 2);
  bf16_t* cq    = (bf16_t*)alloc((size_t)MROWS * 1536 * 2);
  bf16_t* ckv   = (bf16_t*)alloc((size_t)MROWS * 512 * 2);
  bf16_t* qfb   = (bf16_t*)alloc((size_t)NB * NH * S_LEN * DF * 2);
  bf16_t* kfb   = (bf16_t*)alloc((size_t)NB * NH * S_LEN * DF * 2);
  bf16_t* vTb   = (bf16_t*)alloc((size_t)NB * NH * HDIM * S_LEN * 2);
  bf16_t* attb  = (bf16_t*)alloc((size_t)MROWS * 2048 * 2);

  // 1. fused prep: convert x + all 8 transposes in ONE launch
  {
    PrepPack p;
    p.x = x; p.xb = xb;
    p.n4 = (MROWS * 2048) / 4;
    p.convBlocks = (p.n4 + 255) / 256;        // 8192
    int base = 0;
    auto set = [&](int i, const float* s, bf16_t* d, int K, int N) {
      p.d[i] = {s, d, K, N, N / 64, base};
      base += (N / 64) * (K / 64);
    };
    set(0, Wlq, WcatA, 2048, 1536);
    set(1, Wkv, WcatA + (size_t)1536 * 2048, 2048, 512);
    set(2, Wkr, WcatA + (size_t)2048 * 2048, 2048, 1024);
    set(3, Wq,  WcatB, 1536, 2048);
    set(4, Wqr, WcatB + (size_t)2048 * 1536, 1536, 1024);
    set(5, Wk,  WcatC, 512, 2048);
    set(6, Wv,  WcatC + (size_t)2048 * 512, 512, 2048);
    set(7, Wo,  WoT, 2048, 2048);
    prep_all<<<dim3(p.convBlocks + base), dim3(256), 0, stream>>>(p);
  }

  EpiParams ep{}, ep2{};

  // 2. fused: [cq | ckv | kr-rope->kf] = xb @ WcatA^T   (N=3072, K=2048)
  ep = {cq, ckv, kfb, nullptr, bkr, fcos, fsin};
  gemm_db<5><<<dim3(768), dim3(256), 0, stream>>>(xb, WcatA, 3072, 2048, ep);
  // 3+4. fused single launch: {q,qr->qf} and {k->kf, v->vT}
  ep  = {qfb, nullptr, nullptr, nullptr, bqr, fcos, fsin};
  ep2 = {kfb, vTb, nullptr, nullptr, nullptr, nullptr, nullptr};
  gemm_db67<<<dim3(1792), dim3(256), 0, stream>>>(cq, WcatB, ckv, WcatC, ep, ep2);
  // 5. attention
  attn_fwd<<<dim3(512), dim3(256), 0, stream>>>(qfb, kfb, vTb, attb);
  // 6. out = att @ Wo + bo  (f32)
  ep = {nullptr, nullptr, nullptr, out, bo, nullptr, nullptr};
  gemm_db<1><<<dim3(512), dim3(256), 0, stream>>>(attb, WoT, 2048, 2048, ep);
}

// Round 17
// 334.422 us; speedup vs baseline: 1.1384x; 1.0301x over previous
//
#include <hip/hip_runtime.h>
#include <hip/hip_bf16.h>
#include <stdint.h>

#define S_LEN 2048
#define NB 2
#define NH 16
#define HDIM 128
#define RDIM 64
#define DF 192          // HDIM + RDIM
#define MROWS 4096      // NB * S_LEN

typedef __bf16 bf16_t;
typedef __attribute__((ext_vector_type(8))) __bf16 bf16x8;
typedef __attribute__((ext_vector_type(4))) __bf16 bf16x4;
typedef __attribute__((ext_vector_type(4))) float f32x4;
typedef __attribute__((ext_vector_type(4))) float float4v;

__device__ __forceinline__ void gload_lds16(const bf16_t* g, bf16_t* l) {
  __builtin_amdgcn_global_load_lds(
      (const __attribute__((address_space(1))) void*)g,
      (__attribute__((address_space(3))) void*)l, 16, 0, 0);
}

// ---------------- fused prep: convert x (f32->bf16) + all 8 weight transposes ----
struct TrDesc { const float* src; bf16_t* dst; int K; int N; int nbx; int base; };
struct PrepPack {
  const float* x; bf16_t* xb; int n4; int convBlocks;
  TrDesc d[8];
};

__global__ __launch_bounds__(256) void prep_all(PrepPack p) {
  __shared__ float t[64][65];
  const int bid = blockIdx.x;
  if (bid < p.convBlocks) {
    int i = bid * 256 + threadIdx.x;
    if (i >= p.n4) return;
    float4v v = *reinterpret_cast<const float4v*>(&p.x[(size_t)i * 4]);
    bf16x4 o;
    o[0] = (bf16_t)v[0]; o[1] = (bf16_t)v[1]; o[2] = (bf16_t)v[2]; o[3] = (bf16_t)v[3];
    *reinterpret_cast<bf16x4*>(&p.xb[(size_t)i * 4]) = o;
    return;
  }
  const int tb = bid - p.convBlocks;
  int m = 0;
#pragma unroll
  for (int i = 1; i < 8; ++i) m += (tb >= p.d[i].base);
  const TrDesc td = p.d[m];
  const int local = tb - td.base;
  const int n0 = (local % td.nbx) * 64, k0 = (local / td.nbx) * 64;
  const int tx = threadIdx.x & 63, ty = threadIdx.x >> 6;
#pragma unroll
  for (int i = ty; i < 64; i += 4)
    t[i][tx] = td.src[(size_t)(k0 + i) * td.N + n0 + tx];
  __syncthreads();
#pragma unroll
  for (int i = ty; i < 64; i += 4)
    td.dst[(size_t)(n0 + i) * td.K + k0 + tx] = (bf16_t)t[tx][i];
}

// ---------------- shared epilogue ----------------
struct EpiParams {
  bf16_t* o0;
  bf16_t* o1;
  bf16_t* o2;
  float* outf;
  const float* bias;
  const float* cosb;
  const float* sinb;
};

template <int MODE>
__device__ __forceinline__ void epilogue(f32x4 acc[4][4], int N, int m0, int n0,
                                         int mw, int nw, int l15, int lg,
                                         EpiParams ep) {
#pragma unroll
  for (int i = 0; i < 4; ++i)
#pragma unroll
    for (int j = 0; j < 4; ++j) {
      const int col = n0 + nw + j * 16 + l15;
#pragma unroll
      for (int r = 0; r < 4; ++r) {
        const int row = m0 + mw + i * 16 + lg * 4 + r;
        float v = acc[i][j][r];
        const int b = row >> 11, s = row & 2047;
        if constexpr (MODE == 1) {
          ep.outf[(size_t)row * N + col] = v + ep.bias[col];
        } else if constexpr (MODE == 5) {
          if (col < 1536) {
            ep.o0[(size_t)row * 1536 + col] = (bf16_t)v;
          } else if (col < 2048) {
            ep.o1[(size_t)row * 512 + (col - 1536)] = (bf16_t)v;
          } else {
            const int c2 = col - 2048;
            float vb = v + ep.bias[c2];
            float other = __shfl_xor(vb, 1, 64);
            const int h = c2 >> 6, dr = c2 & 63;
            const int fi = dr >> 1;
            const float c = ep.cosb[s * 32 + fi];
            const float sn = ep.sinb[s * 32 + fi];
            const float o = (c2 & 1) ? (other * sn + vb * c) : (vb * c - other * sn);
            ep.o2[(((size_t)(b * NH + h)) * S_LEN + s) * DF + 128 + dr] = (bf16_t)o;
          }
        } else if constexpr (MODE == 6) {
          if (col < 2048) {
            const int h = col >> 7, d = col & 127;
            ep.o0[(((size_t)(b * NH + h)) * S_LEN + s) * DF + d] = (bf16_t)v;
          } else {
            const int c2 = col - 2048;
            float vb = v + ep.bias[c2];
            float other = __shfl_xor(vb, 1, 64);
            const int h = c2 >> 6, dr = c2 & 63;
            const int fi = dr >> 1;
            const float c = ep.cosb[s * 32 + fi];
            const float sn = ep.sinb[s * 32 + fi];
            const float o = (c2 & 1) ? (other * sn + vb * c) : (vb * c - other * sn);
            ep.o0[(((size_t)(b * NH + h)) * S_LEN + s) * DF + 128 + dr] = (bf16_t)o;
          }
        } else {  // MODE 7
          if (col < 2048) {
            const int h = col >> 7, d = col & 127;
            ep.o0[(((size_t)(b * NH + h)) * S_LEN + s) * DF + d] = (bf16_t)v;
          } else {
            const int c2 = col - 2048;
            const int h = c2 >> 7, d = c2 & 127;
            ep.o1[(((size_t)(b * NH + h)) * HDIM + d) * S_LEN + s] = (bf16_t)v;
          }
        }
      }
    }
}

// ---------------- GEMM A: 128x128, BK=64, double-buffered (r10 skeleton) ----------
// 2 blocks/CU. Best measured for 1792-block gemm67 and 512-block gemm1.
template <int MODE>
__device__ __forceinline__ void gemm_body_db(const bf16_t* __restrict__ A,
                                             const bf16_t* __restrict__ Bt,
                                             int N, int K, int m0, int n0,
                                             bf16_t (*Ab)[128 * 64],
                                             bf16_t (*Bb)[128 * 64], EpiParams ep) {
  const int tid = threadIdx.x;
  const int lane = tid & 63, w = tid >> 6;
  const int l15 = lane & 15, lg = lane >> 4;
  const int mw = (w >> 1) * 64, nw = (w & 1) * 64;
  const int nt = K >> 6;

  auto stage = [&](int t, int buf) {
    const int k0 = t << 6;
#pragma unroll
    for (int j = 0; j < 4; ++j) {
      const int s = j * 256 + tid;
      const int row = s >> 3, c = s & 7;
      const int cs = c ^ (row & 7);
      gload_lds16(A + (size_t)(m0 + row) * K + k0 + cs * 8, &Ab[buf][s * 8]);
    }
#pragma unroll
    for (int j = 0; j < 4; ++j) {
      const int s = j * 256 + tid;
      const int row = s >> 3, c = s & 7;
      const int cs = c ^ (row & 7);
      gload_lds16(Bt + (size_t)(n0 + row) * K + k0 + cs * 8, &Bb[buf][s * 8]);
    }
  };

  f32x4 acc[4][4] = {};
  stage(0, 0);

  for (int t = 0; t < nt; ++t) {
    const int cur = t & 1;
    __builtin_amdgcn_s_barrier();
    if (t + 1 < nt) {
      stage(t + 1, cur ^ 1);
      asm volatile("s_waitcnt vmcnt(8)" ::: "memory");
    } else {
      asm volatile("s_waitcnt vmcnt(0)" ::: "memory");
    }
    __builtin_amdgcn_s_barrier();
    __builtin_amdgcn_sched_barrier(0);

    __builtin_amdgcn_s_setprio(1);
#pragma unroll
    for (int kk = 0; kk < 2; ++kk) {
      const int c = kk * 4 + lg;
      bf16x8 a[4], b[4];
#pragma unroll
      for (int i = 0; i < 4; ++i) {
        const int r = mw + i * 16 + l15;
        a[i] = *reinterpret_cast<const bf16x8*>(&Ab[cur][r * 64 + ((c ^ (r & 7)) << 3)]);
      }
#pragma unroll
      for (int j = 0; j < 4; ++j) {
        const int r = nw + j * 16 + l15;
        b[j] = *reinterpret_cast<const bf16x8*>(&Bb[cur][r * 64 + ((c ^ (r & 7)) << 3)]);
      }
#pragma unroll
      for (int i = 0; i < 4; ++i)
#pragma unroll
        for (int j = 0; j < 4; ++j)
          acc[i][j] = __builtin_amdgcn_mfma_f32_16x16x32_bf16(a[i], b[j], acc[i][j], 0, 0, 0);
    }
    __builtin_amdgcn_s_setprio(0);
  }
  epilogue<MODE>(acc, N, m0, n0, mw, nw, l15, lg, ep);
}

template <int MODE>
__global__ __launch_bounds__(256, 2) void gemm_db(const bf16_t* __restrict__ A,
                                                  const bf16_t* __restrict__ Bt,
                                                  int N, int K, EpiParams ep) {
  __shared__ alignas(16) bf16_t Ab[2][128 * 64];
  __shared__ alignas(16) bf16_t Bb[2][128 * 64];
  const int nwg = gridDim.x;
  int f = blockIdx.x;
  f = (f & 7) * (nwg >> 3) + (f >> 3);
  const int nbx = N >> 7;
  const int m0 = (f / nbx) * 128, n0 = (f % nbx) * 128;
  gemm_body_db<MODE>(A, Bt, N, K, m0, n0, Ab, Bb, ep);
}

__global__ __launch_bounds__(256, 2) void gemm_db67(const bf16_t* __restrict__ A6,
                                                    const bf16_t* __restrict__ Bt6,
                                                    const bf16_t* __restrict__ A7,
                                                    const bf16_t* __restrict__ Bt7,
                                                    EpiParams ep6, EpiParams ep7) {
  __shared__ alignas(16) bf16_t Ab[2][128 * 64];
  __shared__ alignas(16) bf16_t Bb[2][128 * 64];
  const int bid = blockIdx.x;
  if (bid < 768) {
    int f = (bid & 7) * 96 + (bid >> 3);
    const int m0 = (f / 24) * 128, n0 = (f % 24) * 128;
    gemm_body_db<6>(A6, Bt6, 3072, 1536, m0, n0, Ab, Bb, ep6);
  } else {
    int b2 = bid - 768;
    int f = (b2 & 7) * 128 + (b2 >> 3);
    const int m0 = (f / 32) * 128, n0 = (f % 32) * 128;
    gemm_body_db<7>(A7, Bt7, 4096, 512, m0, n0, Ab, Bb, ep7);
  }
}

// ---------------- GEMM B: 128x128, BK=32, 3-buffer (r15 skeleton) ----------------
// 3 blocks/CU. Used for gemm5: 768 blocks = EXACTLY one full residency round.
template <int MODE>
__device__ __forceinline__ void gemm_body_3b(const bf16_t* __restrict__ A,
                                             const bf16_t* __restrict__ Bt,
                                             int N, int K, int m0, int n0,
                                             bf16_t (*U)[128 * 64], EpiParams ep) {
  const int tid = threadIdx.x;
  const int lane = tid & 63, w = tid >> 6;
  const int l15 = lane & 15, lg = lane >> 4;
  const int mw = (w >> 1) * 64, nw = (w & 1) * 64;
  const int nt = K >> 5;

  auto stage = [&](int t, int buf) {
    const int k0 = t << 5;
#pragma unroll
    for (int j = 0; j < 4; ++j) {
      const int s = j * 256 + tid;
      const int row = s >> 3, c = s & 7;
      const int cs = c ^ (row & 7);
      const bf16_t* src = (cs < 4)
          ? A + (size_t)(m0 + row) * K + k0 + cs * 8
          : Bt + (size_t)(n0 + row) * K + k0 + (cs - 4) * 8;
      gload_lds16(src, &U[buf][s * 8]);
    }
  };

  f32x4 acc[4][4] = {};
  stage(0, 0);
  stage(1, 1);

  for (int t = 0; t < nt; ++t) {
    const int cur = t % 3;
    if (t + 1 < nt) {
      asm volatile("s_waitcnt vmcnt(4)" ::: "memory");
    } else {
      asm volatile("s_waitcnt vmcnt(0)" ::: "memory");
    }
    __builtin_amdgcn_s_barrier();
    __builtin_amdgcn_sched_barrier(0);
    if (t + 2 < nt) stage(t + 2, (t + 2) % 3);

    bf16x8 a[4], b[4];
#pragma unroll
    for (int i = 0; i < 4; ++i) {
      const int r = mw + i * 16 + l15;
      a[i] = *reinterpret_cast<const bf16x8*>(&U[cur][r * 64 + ((lg ^ (r & 7)) << 3)]);
    }
#pragma unroll
    for (int j = 0; j < 4; ++j) {
      const int r = nw + j * 16 + l15;
      b[j] = *reinterpret_cast<const bf16x8*>(
          &U[cur][r * 64 + (((4 + lg) ^ (r & 7)) << 3)]);
    }
    __builtin_amdgcn_s_setprio(1);
#pragma unroll
    for (int i = 0; i < 4; ++i)
#pragma unroll
      for (int j = 0; j < 4; ++j)
        acc[i][j] = __builtin_amdgcn_mfma_f32_16x16x32_bf16(a[i], b[j], acc[i][j], 0, 0, 0);
    __builtin_amdgcn_s_setprio(0);
  }
  epilogue<MODE>(acc, N, m0, n0, mw, nw, l15, lg, ep);
}

template <int MODE>
__global__ __launch_bounds__(256, 3) void gemm_3b(const bf16_t* __restrict__ A,
                                                  const bf16_t* __restrict__ Bt,
                                                  int N, int K, EpiParams ep) {
  __shared__ alignas(16) bf16_t U[3][128 * 64];   // 48 KB
  const int nwg = gridDim.x;
  int f = blockIdx.x;
  f = (f & 7) * (nwg >> 3) + (f >> 3);
  const int nbx = N >> 7;
  const int m0 = (f / nbx) * 128, n0 = (f % nbx) * 128;
  gemm_body_3b<MODE>(A, Bt, N, K, m0, n0, U, ep);
}

// ---------------- flash attention (causal), swapped softmax, 32q/wave ----------------
__global__ __launch_bounds__(256, 2) void attn_fwd(const bf16_t* __restrict__ qf,
                                                   const bf16_t* __restrict__ kf,
                                                   const bf16_t* __restrict__ vT,
                                                   bf16_t* __restrict__ att) {
  const int tid = threadIdx.x;
  const int lane = tid & 63, w = tid >> 6;   // w: 0..3
  const int l15 = lane & 15, lg = lane >> 4;
  const int l = blockIdx.x;                  // 0..511
  const int bh = (l & 7) * 4 + ((l >> 3) & 3);
  const int qchunk = l >> 5;                 // 0..15
  const int qb0 = (15 - qchunk) * 128;
  const int q0 = qb0 + w * 32;
  const float scale = 0.07216878364870322f;  // 1/sqrt(192)

  __shared__ alignas(16) bf16_t Ks[64 * 192];
  __shared__ alignas(16) bf16_t Vs[128 * 64];
  __shared__ alignas(16) bf16_t Ps[4 * 2048];

  bf16x8 qfr[2][6];
#pragma unroll
  for (int mf = 0; mf < 2; ++mf) {
    const bf16_t* qptr = qf + ((size_t)bh * S_LEN + q0 + mf * 16 + l15) * DF + lg * 8;
#pragma unroll
    for (int d = 0; d < 6; ++d)
      qfr[mf][d] = *reinterpret_cast<const bf16x8*>(qptr + d * 32);
  }

  f32x4 o[2][8] = {};
  float mrun[2] = {-1e30f, -1e30f}, lsum[2] = {0.0f, 0.0f};

  const bf16_t* kb0 = kf + (size_t)bh * S_LEN * DF;
  const bf16_t* vb0 = vT + (size_t)bh * HDIM * S_LEN;
  const int njt = qb0 / 64 + 2;
  const int wslot = tid & ~63;

  for (int jt = 0; jt < njt; ++jt) {
    const int j0 = jt * 64;
    __syncthreads();
    const bf16_t* kTile = kb0 + (size_t)j0 * DF;
#pragma unroll
    for (int i = 0; i < 6; ++i) {
      const int s = i * 256 + tid;
      const int row = s / 24;
      const int c = s - row * 24;
      const int cs = c ^ (row & 7);
      gload_lds16(kTile + (size_t)row * DF + cs * 8,
                  Ks + (size_t)(i * 256 + wslot) * 8);
    }
    const bf16_t* vTile = vb0 + j0;
#pragma unroll
    for (int i = 0; i < 4; ++i) {
      const int s = i * 256 + tid;
      const int row = s >> 3;
      const int c = s & 7;
      const int cs = c ^ (row & 7);
      gload_lds16(vTile + (size_t)row * S_LEN + cs * 8,
                  Vs + (size_t)(i * 256 + wslot) * 8);
    }
    __syncthreads();

    if (j0 > q0 + 31) continue;

    f32x4 sa[2][4] = {};
    __builtin_amdgcn_s_setprio(1);
#pragma unroll
    for (int jf = 0; jf < 4; ++jf) {
      const int krow = jf * 16 + l15;
      const int ksw = krow & 7;
#pragma unroll
      for (int d = 0; d < 6; ++d) {
        const int kc = (4 * d + lg) ^ ksw;
        bf16x8 kfr = *reinterpret_cast<const bf16x8*>(&Ks[krow * 192 + kc * 8]);
#pragma unroll
        for (int mf = 0; mf < 2; ++mf)
          sa[mf][jf] =
              __builtin_amdgcn_mfma_f32_16x16x32_bf16(kfr, qfr[mf][d], sa[mf][jf], 0, 0, 0);
      }
    }
    __builtin_amdgcn_s_setprio(0);

#pragma unroll
    for (int mf = 0; mf < 2; ++mf) {
      const int qi = q0 + mf * 16 + l15;
      const bool full = (j0 + 63 <= q0 + mf * 16);
      float sv[16];
#pragma unroll
      for (int jf = 0; jf < 4; ++jf)
#pragma unroll
        for (int r = 0; r < 4; ++r) {
          float x = sa[mf][jf][r] * scale;
          if (!full) {
            const int j = j0 + jf * 16 + lg * 4 + r;
            if (j > qi) x = -1e30f;
          }
          sv[jf * 4 + r] = x;
        }

      float a8[8];
#pragma unroll
      for (int i = 0; i < 8; ++i) a8[i] = fmaxf(sv[i], sv[i + 8]);
#pragma unroll
      for (int i = 0; i < 4; ++i) a8[i] = fmaxf(a8[i], a8[i + 4]);
      float mx = fmaxf(fmaxf(a8[0], a8[1]), fmaxf(a8[2], a8[3]));
      mx = fmaxf(mx, __shfl_xor(mx, 16, 64));
      mx = fmaxf(mx, __shfl_xor(mx, 32, 64));

      if (__any(mx > mrun[mf] + 8.0f)) {
        const float mn = fmaxf(mrun[mf], mx);
        const float alpha = __expf(mrun[mf] - mn);
        mrun[mf] = mn;
        lsum[mf] *= alpha;
        float af[4];
#pragma unroll
        for (int r = 0; r < 4; ++r) af[r] = __shfl(alpha, lg * 4 + r, 16);
#pragma unroll
        for (int dt = 0; dt < 8; ++dt)
#pragma unroll
          for (int r = 0; r < 4; ++r) o[mf][dt][r] *= af[r];
      }

#pragma unroll
      for (int i = 0; i < 16; ++i) sv[i] = __expf(sv[i] - mrun[mf]);
      float s8[8];
#pragma unroll
      for (int i = 0; i < 8; ++i) s8[i] = sv[i] + sv[i + 8];
#pragma unroll
      for (int i = 0; i < 4; ++i) s8[i] = s8[i] + s8[i + 4];
      float sm = (s8[0] + s8[1]) + (s8[2] + s8[3]);
      sm += __shfl_xor(sm, 16, 64);
      sm += __shfl_xor(sm, 32, 64);
      lsum[mf] += sm;

#pragma unroll
      for (int jf = 0; jf < 4; ++jf) {
        bf16x4 pk;
#pragma unroll
        for (int r = 0; r < 4; ++r) pk[r] = (bf16_t)sv[jf * 4 + r];
        const int key = jf * 16 + lg * 4;
        *reinterpret_cast<bf16x4*>(
            &Ps[w * 2048 + mf * 1024 + l15 * 64 + (key ^ ((l15 & 7) << 3))]) = pk;
      }
    }
    asm volatile("s_waitcnt lgkmcnt(0)" ::: "memory");
    __builtin_amdgcn_sched_barrier(0);
    bf16x8 pfr[2][2];
#pragma unroll
    for (int mf = 0; mf < 2; ++mf)
#pragma unroll
      for (int jk = 0; jk < 2; ++jk)
        pfr[mf][jk] = *reinterpret_cast<const bf16x8*>(
            &Ps[w * 2048 + mf * 1024 + l15 * 64 + (((jk * 4 + lg) ^ (l15 & 7)) << 3)]);

    __builtin_amdgcn_s_setprio(1);
#pragma unroll
    for (int dt = 0; dt < 8; ++dt) {
      const int vrow = dt * 16 + l15;
      const int vsw = vrow & 7;
#pragma unroll
      for (int jk = 0; jk < 2; ++jk) {
        const int vc = (jk * 4 + lg) ^ vsw;
        bf16x8 vfr = *reinterpret_cast<const bf16x8*>(&Vs[vrow * 64 + vc * 8]);
#pragma unroll
        for (int mf = 0; mf < 2; ++mf)
          o[mf][dt] =
              __builtin_amdgcn_mfma_f32_16x16x32_bf16(pfr[mf][jk], vfr, o[mf][dt], 0, 0, 0);
      }
    }
    __builtin_amdgcn_s_setprio(0);
  }

  const int b = bh >> 4, h = bh & 15;
#pragma unroll
  for (int mf = 0; mf < 2; ++mf) {
    const float inv = 1.0f / lsum[mf];
    float iv[4];
#pragma unroll
    for (int r = 0; r < 4; ++r) iv[r] = __shfl(inv, lg * 4 + r, 16);
#pragma unroll
    for (int dt = 0; dt < 8; ++dt)
#pragma unroll
      for (int r = 0; r < 4; ++r) {
        const int s = q0 + mf * 16 + lg * 4 + r;
        att[((size_t)b * S_LEN + s) * 2048 + h * 128 + dt * 16 + l15] =
            (bf16_t)(o[mf][dt][r] * iv[r]);
      }
  }
}

// ---------------- host launch ----------------
extern "C" void kernel_launch(void* const* d_in, const int* in_sizes, int n_in,
                              void* d_out, int out_size, void* d_ws, size_t ws_size,
                              hipStream_t stream) {
  const float* x    = (const float*)d_in[0];
  const float* fcos = (const float*)d_in[1];
  const float* fsin = (const float*)d_in[2];
  const float* Wkv  = (const float*)d_in[3];
  const float* Wlq  = (const float*)d_in[4];
  const float* Wq   = (const float*)d_in[5];
  const float* Wk   = (const float*)d_in[6];
  const float* Wv   = (const float*)d_in[7];
  const float* Wqr  = (const float*)d_in[8];
  const float* bqr  = (const float*)d_in[9];
  const float* Wkr  = (const float*)d_in[10];
  const float* bkr  = (const float*)d_in[11];
  const float* Wo   = (const float*)d_in[12];
  const float* bo   = (const float*)d_in[13];
  float* out = (float*)d_out;

  char* ws = (char*)d_ws;
  size_t off = 0;
  auto alloc = [&](size_t bytes) {
    void* p = ws + off;
    off += (bytes + 255) & ~(size_t)255;
    return p;
  };
  bf16_t* xb    = (bf16_t*)alloc((size_t)MROWS * 2048 * 2);
  bf16_t* WcatA = (bf16_t*)alloc((size_t)3072 * 2048 * 2);  // [Wlq|Wkv|Wkr]^T, K=2048
  bf16_t* WcatB = (bf16_t*)alloc((size_t)3072 * 1536 * 2);  // [Wq|Wqr]^T,     K=1536
  bf16_t* WcatC = (bf16_t*)alloc((size_t)4096 * 512 * 2);   // [Wk|Wv]^T,      K=512
  bf16_t* WoT   = (bf16_t*)alloc((size_t)2048 * 2048 * 2);
  bf16_t* cq    = (bf16_t*)alloc((size_t)MROWS * 1536 * 2);
  bf16_t* ckv   = (bf16_t*)alloc((size_t)MROWS * 512 * 2);
  bf16_t* qfb   = (bf16_t*)alloc((size_t)NB * NH * S_LEN * DF * 2);
  bf16_t* kfb   = (bf16_t*)alloc((size_t)NB * NH * S_LEN * DF * 2);
  bf16_t* vTb   = (bf16_t*)alloc((size_t)NB * NH * HDIM * S_LEN * 2);
  bf16_t* attb  = (bf16_t*)alloc((size_t)MROWS * 2048 * 2);

  // 1. fused prep: convert x + all 8 transposes in ONE launch
  {
    PrepPack p;
    p.x = x; p.xb = xb;
    p.n4 = (MROWS * 2048) / 4;
    p.convBlocks = (p.n4 + 255) / 256;        // 8192
    int base = 0;
    auto set = [&](int i, const float* s, bf16_t* d, int K, int N) {
      p.d[i] = {s, d, K, N, N / 64, base};
      base += (N / 64) * (K / 64);
    };
    set(0, Wlq, WcatA, 2048, 1536);
    set(1, Wkv, WcatA + (size_t)1536 * 2048, 2048, 512);
    set(2, Wkr, WcatA + (size_t)2048 * 2048, 2048, 1024);
    set(3, Wq,  WcatB, 1536, 2048);
    set(4, Wqr, WcatB + (size_t)2048 * 1536, 1536, 1024);
    set(5, Wk,  WcatC, 512, 2048);
    set(6, Wv,  WcatC + (size_t)2048 * 512, 512, 2048);
    set(7, Wo,  WoT, 2048, 2048);
    prep_all<<<dim3(p.convBlocks + base), dim3(256), 0, stream>>>(p);
  }

  EpiParams ep{}, ep2{};

  // 2. fused: [cq | ckv | kr-rope->kf] = xb @ WcatA^T  (N=3072, K=2048)
  //    3-buffer kernel: 768 blocks @ 3/CU = exactly one residency round (no tail).
  ep = {cq, ckv, kfb, nullptr, bkr, fcos, fsin};
  gemm_3b<5><<<dim3(768), dim3(256), 0, stream>>>(xb, WcatA, 3072, 2048, ep);
  // 3+4. fused single launch: {q,qr->qf} and {k->kf, v->vT}  (r10 dbuf kernel)
  ep  = {qfb, nullptr, nullptr, nullptr, bqr, fcos, fsin};
  ep2 = {kfb, vTb, nullptr, nullptr, nullptr, nullptr, nullptr};
  gemm_db67<<<dim3(1792), dim3(256), 0, stream>>>(cq, WcatB, ckv, WcatC, ep, ep2);
  // 5. attention
  attn_fwd<<<dim3(512), dim3(256), 0, stream>>>(qfb, kfb, vTb, attb);
  // 6. out = att @ Wo + bo  (f32)  (r10 dbuf kernel, 512 blocks = one round @2/CU)
  ep = {nullptr, nullptr, nullptr, out, bo, nullptr, nullptr};
  gemm_db<1><<<dim3(512), dim3(256), 0, stream>>>(attb, WoT, 2048, 2048, ep);
}